// Round 4
// baseline (292.165 us; speedup 1.0000x reference)
//
#include <hip/hip_runtime.h>
#include <hip/hip_bf16.h>
#include <float.h>

// EdgeConv (fp32 I/O):
//   out[b,o,n] = P[b,n,o] + max_{j<20} Q[b, idx[b,n,j], o]
//   P = (W1-W2)^T x + b ; Q = W2^T x
//   knn: top-20 smallest of score[m] = sq[m] - 2*x_n.x_m  (m != n)
// Round 18: revert pass-B compaction to the R1-proven ballot form (atomic
// variant was wall-neutral but stall-prone / profile-hostile). Diagnostic
// ILP round: the per-chunk dep chain (loads -> 2-3 serial MFMA -> fmaf ->
// cmp) is only partially covered at ~3.6 waves/SIMD; #pragma unroll 2 on
// both mc loops gives two independent chains (VGPR headroom: count=48).
// Free pass-A cut: fminf-merge the two ti values before the min2 update
// (pool still = 16 lanes x 2 distinct cands; tau weakly larger, CAP ok).
// tau = 20th of 32-pool (+PAD 1.0 >= fp16-hi err bound). CAP 64.
// Planes hold y = sqrt(2)*x fp16x2, tiled [b][n>>4][k>>3][n&15][k&7].

#define BB 8
#define FF 64
#define NN 4096
#define KK 20
#define CAP 64
#define SS 4
#define PAD 1.0f

typedef unsigned short ushort_t;
typedef unsigned long long u64;
typedef __attribute__((ext_vector_type(8))) _Float16 half8;
typedef __attribute__((ext_vector_type(4))) float floatx4;
typedef __attribute__((ext_vector_type(2))) float floatx2;
typedef __attribute__((ext_vector_type(2))) unsigned short ushortx2;
typedef __attribute__((ext_vector_type(4))) unsigned int uintx4;

// plane flat index (shorts): [b][n>>4][k>>3][n&15][k&7]
__device__ __forceinline__ size_t plidx16(int b, int n, int k) {
  return ((size_t)b * 256 + (n >> 4)) * 1024 + (size_t)(k >> 3) * 128 + (size_t)(n & 15) * 8 + (k & 7);
}

// ---------------- prep: sq, Q, fp16x2 planes of y = sqrt(2)*x ----------------
__global__ void __launch_bounds__(256) prep_kernel(
    const float* __restrict__ x, const float* __restrict__ W,
    float* __restrict__ sq, float* __restrict__ Q,
    ushort_t* __restrict__ ph, ushort_t* __restrict__ pm)
{
  __shared__ float xs[64][65];
  __shared__ float w2[64][65];
  int t = threadIdx.x;
  int b = blockIdx.x >> 6;
  int n0 = (blockIdx.x & 63) << 6;
  const float* xb = x + (size_t)b * FF * NN;

  int nl = t & 63, fq = t >> 6;
  #pragma unroll
  for (int i = 0; i < 16; ++i) {
    int f = fq + i * 4;
    xs[f][nl] = xb[(size_t)f * NN + n0 + nl];
  }
  #pragma unroll
  for (int i = 0; i < 16; ++i) {
    int id = i * 256 + t;            // 0..4095
    int o = id >> 6, f = id & 63;
    w2[o][f] = W[o * 128 + 64 + f];  // W2
  }
  __syncthreads();

  if (t < 64) {
    float s = 0.f;
    #pragma unroll
    for (int f = 0; f < FF; ++f) { float v = xs[f][t]; s += v * v; }
    sq[b * NN + n0 + t] = s;
  }
  int o = t & 63, g = t >> 6;
  for (int i = 0; i < 16; ++i) {
    int r = g + i * 4;
    int n = n0 + r;
    float acc = 0.f;
    #pragma unroll
    for (int f = 0; f < FF; ++f) acc += w2[o][f] * xs[f][r];
    Q[((size_t)b * NN + n) * FF + o] = acc;

    // fp16x2 split of y = sqrt(2)*x: y = h + m*2^-12 (m stored pre-scaled by 4096)
    float v = xs[o][r] * 1.41421356237309515f;
    _Float16 hh = (_Float16)v;
    float hf = (float)hh;
    _Float16 mm = (_Float16)((v - hf) * 4096.0f);
    size_t pb = plidx16(b, n, o);
    ph[pb] = __builtin_bit_cast(unsigned short, hh);
    pm[pb] = __builtin_bit_cast(unsigned short, mm);
  }
}

// ascending bitonic sort of 32 floats as elements (2l, 2l+1) across 16 lanes
__device__ __forceinline__ void bitonic32f(float& v0, float& v1, int l15)
{
  #pragma unroll
  for (int k = 2; k <= 32; k <<= 1) {
    #pragma unroll
    for (int j = k >> 1; j >= 1; j >>= 1) {
      bool dirup = ((2 * l15) & k) == 0;
      if (j >= 2) {
        int lj = j >> 1;
        float p0 = __shfl_xor(v0, lj, 16);
        float p1 = __shfl_xor(v1, lj, 16);
        bool lower = (l15 & lj) == 0;
        bool keepmin = (dirup == lower);
        v0 = keepmin ? fminf(v0, p0) : fmaxf(v0, p0);
        v1 = keepmin ? fminf(v1, p1) : fmaxf(v1, p1);
      } else {
        float lo = fminf(v0, v1), hi = fmaxf(v0, v1);
        v0 = dirup ? lo : hi;
        v1 = dirup ? hi : lo;
      }
    }
  }
}

// ascending bitonic sort of 64 u64 keys as elements (2l, 2l+1) across 32 lanes
__device__ __forceinline__ void bitonic64k(u64& v0, u64& v1, int l31)
{
  #pragma unroll
  for (int k = 2; k <= 64; k <<= 1) {
    #pragma unroll
    for (int j = k >> 1; j >= 1; j >>= 1) {
      bool dirup = ((2 * l31) & k) == 0;
      if (j >= 2) {
        int lj = j >> 1;
        u64 p0 = __shfl_xor(v0, lj, 32);
        u64 p1 = __shfl_xor(v1, lj, 32);
        bool lower = (l31 & lj) == 0;
        bool keepmin = (dirup == lower);
        u64 a0 = v0 < p0 ? v0 : p0, b0 = v0 < p0 ? p0 : v0;
        u64 a1 = v1 < p1 ? v1 : p1, b1 = v1 < p1 ? p1 : v1;
        v0 = keepmin ? a0 : b0;
        v1 = keepmin ? a1 : b1;
      } else {
        u64 lo = v0 < v1 ? v0 : v1, hi = v0 < v1 ? v1 : v0;
        v0 = dirup ? lo : hi;
        v1 = dirup ? hi : lo;
      }
    }
  }
}

// monotone u64 key: (order-preserving f32 bits << 16) | col (col < 4096)
__device__ __forceinline__ u64 mkkey(float d, unsigned short idx)
{
  unsigned ub = __float_as_uint(d);
  unsigned mono = ub ^ (0x80000000u | (unsigned)((int)ub >> 31));
  return ((u64)mono << 16) | idx;
}

// ---------------- knn: two-pass threshold filter, 16 rows/wave ----------------
__global__ void __launch_bounds__(256) knn_kernel(
    const ushort_t* __restrict__ ph, const ushort_t* __restrict__ pm,
    const float* __restrict__ sq, u64* __restrict__ keys2)
{
  __shared__ float    bufd[4][16][CAP];   // 16384 B
  __shared__ ushort_t bufi[4][16][CAP];   //  8192 B
  __shared__ int scnt[4][16];

  const int t = threadIdx.x;
  const int lane = t & 63;
  const int l15 = lane & 15;
  const int q = lane >> 4;          // quarter 0..3 (C rows 4q..4q+3)
  const int wv = t >> 6;
  const int blk = blockIdx.x;
  const int slice = blk & 3;
  const int g = (blk >> 2) & 63;    // 64 groups per batch
  const int b = blk >> 8;
  const int n0w = (g * 4 + wv) * 16;   // this wave's 16-row tile

  const float* __restrict__ sqb = sq + (size_t)b * NN;
  const float MS = 2.44140625e-4f;   // 2^-12
  const int laneoff = q * 128 + l15 * 8;

  // diagonal (self) lives in exactly one chunk of one slice for this wave
  const bool hasdiag = ((n0w >> 10) == slice);
  const int dmc = (n0w & 1023) >> 5;

  // resident A fragments: row = l15, k = 32s + 8q + e ; NEGATED so the MFMA
  // accumulates  sq_m - y_n.y_m  directly (C-init = sq_m).
  half8 Ah[2], Am[2];
  {
    size_t abase = ((size_t)b * 256 + (n0w >> 4)) * 1024 + laneoff;
    #pragma unroll
    for (int s = 0; s < 2; ++s) {
      Ah[s] = *(const half8*)(ph + abase + s * 512);
      Am[s] = *(const half8*)(pm + abase + s * 512);
      uintx4 uh = __builtin_bit_cast(uintx4, Ah[s]); uh ^= 0x80008000u;
      uintx4 um = __builtin_bit_cast(uintx4, Am[s]); um ^= 0x80008000u;
      Ah[s] = __builtin_bit_cast(half8, uh);
      Am[s] = __builtin_bit_cast(half8, um);
    }
  }

  // -------- pass A (fp16-hi only): per-lane min2 per row over 32 chunks --------
  // pool = 32 values (16 lanes x best-2 of each lane's candidates, at most
  // one per (chunk,r) after the ti-merge); 20 smallest pool entries are
  // distinct candidates -> >=20 cands <= tau.
  float m1[4], m2[4];
  #pragma unroll
  for (int r = 0; r < 4; ++r) { m1[r] = FLT_MAX; m2[r] = FLT_MAX; }

  #pragma unroll 2
  for (int mc = 0; mc < 32; ++mc) {
    const int m0 = slice * 1024 + mc * 32;
    size_t mbase = ((size_t)b * 256 + (m0 >> 4)) * 1024 + laneoff;
    float sv0 = sqb[m0 + l15];
    float sv1 = sqb[m0 + 16 + l15];
    floatx4 a1[2];
    #pragma unroll
    for (int e = 0; e < 4; ++e) { a1[0][e] = sv0; a1[1][e] = sv1; }
    #pragma unroll
    for (int ti = 0; ti < 2; ++ti) {
      #pragma unroll
      for (int s = 0; s < 2; ++s) {
        half8 Bh = *(const half8*)(ph + mbase + ti * 1024 + s * 512);
        a1[ti] = __builtin_amdgcn_mfma_f32_16x16x32_f16(Ah[s], Bh, a1[ti], 0, 0, 0);
      }
    }
    if (hasdiag && mc == dmc) {
      #pragma unroll
      for (int ti = 0; ti < 2; ++ti) {
        int mcol = m0 + 16 * ti + l15;
        #pragma unroll
        for (int r = 0; r < 4; ++r)
          if (mcol == n0w + 4 * q + r) a1[ti][r] = FLT_MAX;
      }
    }
    #pragma unroll
    for (int r = 0; r < 4; ++r) {
      float c = fminf(a1[0][r], a1[1][r]);
      m2[r] = __builtin_amdgcn_fmed3f(c, m1[r], m2[r]);  // min2 update
      m1[r] = fminf(m1[r], c);
    }
  }

  // tau_r = 20th of 32-pool (approx) + PAD; PAD >= max fp16-hi distance error
  float taupad[4];
  #pragma unroll
  for (int r = 0; r < 4; ++r) {
    float v0 = m1[r], v1 = m2[r];
    bitonic32f(v0, v1, l15);
    taupad[r] = __shfl(v1, 9, 16) + PAD;   // element 19 = lane 9, reg 1
  }

  // -------- pass B: exact fp16x2 recompute, ballot-compact into LDS --------
  int cnt[4];
  #pragma unroll
  for (int r = 0; r < 4; ++r) cnt[r] = 0;

  #pragma unroll 2
  for (int mc = 0; mc < 32; ++mc) {
    const int m0 = slice * 1024 + mc * 32;
    size_t mbase = ((size_t)b * 256 + (m0 >> 4)) * 1024 + laneoff;
    float sv0 = sqb[m0 + l15];
    float sv1 = sqb[m0 + 16 + l15];
    floatx4 a1[2], a2[2];
    #pragma unroll
    for (int e = 0; e < 4; ++e) {
      a1[0][e] = sv0; a1[1][e] = sv1;
      a2[0][e] = 0.f; a2[1][e] = 0.f;
    }
    #pragma unroll
    for (int ti = 0; ti < 2; ++ti) {
      #pragma unroll
      for (int s = 0; s < 2; ++s) {
        half8 Bh = *(const half8*)(ph + mbase + ti * 1024 + s * 512);
        half8 Bm = *(const half8*)(pm + mbase + ti * 1024 + s * 512);
        a1[ti] = __builtin_amdgcn_mfma_f32_16x16x32_f16(Ah[s], Bh, a1[ti], 0, 0, 0);
        a2[ti] = __builtin_amdgcn_mfma_f32_16x16x32_f16(Am[s], Bh, a2[ti], 0, 0, 0);
        a2[ti] = __builtin_amdgcn_mfma_f32_16x16x32_f16(Ah[s], Bm, a2[ti], 0, 0, 0);
      }
    }
    // exact cand = a1 + MS*a2, in place
    #pragma unroll
    for (int ti = 0; ti < 2; ++ti)
      #pragma unroll
      for (int r = 0; r < 4; ++r)
        a1[ti][r] = __builtin_fmaf(MS, a2[ti][r], a1[ti][r]);
    if (hasdiag && mc == dmc) {
      #pragma unroll
      for (int ti = 0; ti < 2; ++ti) {
        int mcol = m0 + 16 * ti + l15;
        #pragma unroll
        for (int r = 0; r < 4; ++r)
          if (mcol == n0w + 4 * q + r) a1[ti][r] = FLT_MAX;
      }
    }
    #pragma unroll
    for (int ti = 0; ti < 2; ++ti) {
      int mcol = m0 + 16 * ti + l15;
      #pragma unroll
      for (int r = 0; r < 4; ++r) {
        bool ok = a1[ti][r] <= taupad[r];
        unsigned long long bal = __ballot(ok);
        unsigned mh = (unsigned)((bal >> (q * 16)) & 0xFFFFull);
        int pre = __popc(mh & ((1u << l15) - 1u));
        int slot = cnt[r] + pre;
        if (ok && slot < CAP) {
          bufd[wv][4 * q + r][slot] = a1[ti][r];
          bufi[wv][4 * q + r][slot] = (ushort_t)mcol;
        }
        cnt[r] += __popc(mh);
      }
    }
  }

  if (l15 == 0) {
    #pragma unroll
    for (int r = 0; r < 4; ++r) scnt[wv][4 * q + r] = cnt[r];
  }
  __builtin_amdgcn_s_waitcnt(0);   // drain LDS writes (same-wave read below)

  // -------- final: per half-wave, sort 8 rows' survivors, emit sorted top-20 --------
  const int l31 = t & 31;
  const int hfw = (t >> 5) & 1;
  #pragma unroll
  for (int i = 0; i < 8; ++i) {
    int rloc = hfw * 8 + i;
    int c = scnt[wv][rloc];
    c = c < CAP ? c : CAP;
    floatx2  dv = *(const floatx2*)&bufd[wv][rloc][2 * l31];
    ushortx2 iv = *(const ushortx2*)&bufi[wv][rloc][2 * l31];
    u64 k0 = (2 * l31     < c) ? mkkey(dv[0], iv[0]) : ~0ull;
    u64 k1 = (2 * l31 + 1 < c) ? mkkey(dv[1], iv[1]) : ~0ull;
    bitonic64k(k0, k1, l31);
    u64 a = __shfl(k0, l31 >> 1, 32);
    u64 b2 = __shfl(k1, l31 >> 1, 32);
    u64 kv = (l31 & 1) ? b2 : a;              // element l31 of sorted order
    if (l31 < KK) {
      size_t rowg = ((size_t)b * NN + n0w + rloc) * SS + slice;
      keys2[rowg * KK + l31] = kv;
    }
  }
}

// ---------------- merge four sorted 20-key lists per row ----------------
__global__ void __launch_bounds__(256) merge_kernel(
    const u64* __restrict__ keys2, int* __restrict__ idxOut)
{
  int row = blockIdx.x * 256 + threadIdx.x;   // 0..32767
  if (row >= BB * NN) return;
  u64 h[SS]; int p[SS];
  #pragma unroll
  for (int s = 0; s < SS; ++s) {
    p[s] = 0;
    h[s] = keys2[((size_t)row * SS + s) * KK];
  }
  int* op = idxOut + (size_t)row * KK;
  #pragma unroll
  for (int q = 0; q < KK; ++q) {
    int bs = 0;
    u64 bv = h[0];
    #pragma unroll
    for (int s = 1; s < SS; ++s) { if (h[s] < bv) { bv = h[s]; bs = s; } }
    op[q] = (int)(bv & 0xFFFFull);            // col in low 16 bits
    p[bs]++;
    h[bs] = (p[bs] < KK) ? keys2[((size_t)row * SS + bs) * KK + p[bs]] : ~0ull;
  }
}

// ---------------- gather: out[b,o,n] = P + max_j Q[nbr_j] ----------------
__global__ void __launch_bounds__(256) gather_kernel(
    const float* __restrict__ x, const float* __restrict__ W,
    const float* __restrict__ bias,
    const float* __restrict__ Q, const int* __restrict__ idxIn,
    float* __restrict__ out)
{
  __shared__ float xs[64][65];
  __shared__ float wp[64][65];
  __shared__ float ot[64][65];
  __shared__ float bs[64];
  int t = threadIdx.x;
  int b = blockIdx.x >> 6;
  int n0 = (blockIdx.x & 63) << 6;
  const float* xb = x + (size_t)b * FF * NN;

  int nl0 = t & 63, fq = t >> 6;
  #pragma unroll
  for (int i = 0; i < 16; ++i) {
    int f = fq + i * 4;
    xs[f][nl0] = xb[(size_t)f * NN + n0 + nl0];
  }
  #pragma unroll
  for (int i = 0; i < 16; ++i) {
    int id = i * 256 + t;            // 0..4095
    int o = id >> 6, f = id & 63;
    wp[o][f] = W[o * 128 + f] - W[o * 128 + 64 + f];   // W1 - W2
  }
  if (t < 64) bs[t] = bias[t];
  __syncthreads();

  int o = t & 63, g = t >> 6;
  for (int i = 0; i < 16; ++i) {
    int nl = g + i * 4;
    int n = n0 + nl;
    float p = bs[o];
    #pragma unroll
    for (int f = 0; f < FF; ++f) p += wp[o][f] * xs[f][nl];
    const int* ip = idxIn + ((size_t)b * NN + n) * KK;
    float m = -FLT_MAX;
    #pragma unroll
    for (int j = 0; j < KK; ++j) {
      int nb = ip[j];                                   // wave-uniform
      m = fmaxf(m, Q[((size_t)b * NN + nb) * FF + o]);  // 256B coalesced
    }
    ot[nl][o] = p + m;
  }
  __syncthreads();
  for (int i = 0; i < 16; ++i) {
    int o2 = g + i * 4;
    int nl = t & 63;
    out[((size_t)b * FF + o2) * NN + n0 + nl] = ot[nl][o2];
  }
}

extern "C" void kernel_launch(void* const* d_in, const int* in_sizes, int n_in,
                              void* d_out, int out_size, void* d_ws, size_t ws_size,
                              hipStream_t stream)
{
  const float* x    = (const float*)d_in[0];
  const float* W    = (const float*)d_in[1];
  const float* bias = (const float*)d_in[2];
  float* out = (float*)d_out;

  int*   idxb = (int*)d_ws;                               // 8*4096*20
  float* sq   = (float*)(idxb + (size_t)BB * NN * KK);    // 8*4096
  float* Q    = sq + (size_t)BB * NN;                     // 8*4096*64
  ushort_t* ph = (ushort_t*)(Q + (size_t)BB * NN * FF);   // 8*4096*64 each
  ushort_t* pm = ph + (size_t)BB * NN * FF;
  u64*   keys2 = (u64*)(pm + (size_t)BB * NN * FF);       // 8*4096*4*20

  prep_kernel<<<BB * (NN / 64), 256, 0, stream>>>(x, W, sq, Q, ph, pm);
  knn_kernel<<<BB * 64 * SS, 256, 0, stream>>>(ph, pm, sq, keys2);   // 2048 blocks
  merge_kernel<<<(BB * NN + 255) / 256, 256, 0, stream>>>(keys2, idxb);
  gather_kernel<<<BB * (NN / 64), 256, 0, stream>>>(x, W, bias, Q, idxb, out);
}

// Round 5
// 286.038 us; speedup vs baseline: 1.0214x; 1.0214x over previous
//
#include <hip/hip_runtime.h>
#include <hip/hip_bf16.h>
#include <float.h>

// EdgeConv (fp32 I/O):
//   out[b,o,n] = P[b,n,o] + max_{j<20} Q[b, idx[b,n,j], o]
//   P = (W1-W2)^T x + b ; Q = W2^T x
//   knn: top-20 smallest of score[m] = sq[m] - 2*x_n.x_m  (m != n)
// Round 19 (attribution): R4's unroll-2 regressed (292 us) -> reverted.
// Evidence so far: VALU-instr cuts stopped paying (R3 wall-neutral) ->
// latency/dependency-bound, but the fused kernel gives no attribution
// between pass A, pass B+compaction, and the bitonic sorts. Split knn
// into knn_a (pass A + tau -> global, ~0 LDS => occupancy experiment)
// and knn_b (pass B + sort + emit). tau overlays the idx workspace
// (written later by merge). sq staged in LDS for knn_a.
// tau = 20th of 32-pool (+PAD 1.0 >= fp16-hi err bound). CAP 64.
// Planes hold y = sqrt(2)*x fp16x2, tiled [b][n>>4][k>>3][n&15][k&7].

#define BB 8
#define FF 64
#define NN 4096
#define KK 20
#define CAP 64
#define SS 4
#define PAD 1.0f

typedef unsigned short ushort_t;
typedef unsigned long long u64;
typedef __attribute__((ext_vector_type(8))) _Float16 half8;
typedef __attribute__((ext_vector_type(4))) float floatx4;
typedef __attribute__((ext_vector_type(2))) float floatx2;
typedef __attribute__((ext_vector_type(2))) unsigned short ushortx2;
typedef __attribute__((ext_vector_type(4))) unsigned int uintx4;

// plane flat index (shorts): [b][n>>4][k>>3][n&15][k&7]
__device__ __forceinline__ size_t plidx16(int b, int n, int k) {
  return ((size_t)b * 256 + (n >> 4)) * 1024 + (size_t)(k >> 3) * 128 + (size_t)(n & 15) * 8 + (k & 7);
}

// ---------------- prep: sq, Q, fp16x2 planes of y = sqrt(2)*x ----------------
__global__ void __launch_bounds__(256) prep_kernel(
    const float* __restrict__ x, const float* __restrict__ W,
    float* __restrict__ sq, float* __restrict__ Q,
    ushort_t* __restrict__ ph, ushort_t* __restrict__ pm)
{
  __shared__ float xs[64][65];
  __shared__ float w2[64][65];
  int t = threadIdx.x;
  int b = blockIdx.x >> 6;
  int n0 = (blockIdx.x & 63) << 6;
  const float* xb = x + (size_t)b * FF * NN;

  int nl = t & 63, fq = t >> 6;
  #pragma unroll
  for (int i = 0; i < 16; ++i) {
    int f = fq + i * 4;
    xs[f][nl] = xb[(size_t)f * NN + n0 + nl];
  }
  #pragma unroll
  for (int i = 0; i < 16; ++i) {
    int id = i * 256 + t;            // 0..4095
    int o = id >> 6, f = id & 63;
    w2[o][f] = W[o * 128 + 64 + f];  // W2
  }
  __syncthreads();

  if (t < 64) {
    float s = 0.f;
    #pragma unroll
    for (int f = 0; f < FF; ++f) { float v = xs[f][t]; s += v * v; }
    sq[b * NN + n0 + t] = s;
  }
  int o = t & 63, g = t >> 6;
  for (int i = 0; i < 16; ++i) {
    int r = g + i * 4;
    int n = n0 + r;
    float acc = 0.f;
    #pragma unroll
    for (int f = 0; f < FF; ++f) acc += w2[o][f] * xs[f][r];
    Q[((size_t)b * NN + n) * FF + o] = acc;

    // fp16x2 split of y = sqrt(2)*x: y = h + m*2^-12 (m stored pre-scaled by 4096)
    float v = xs[o][r] * 1.41421356237309515f;
    _Float16 hh = (_Float16)v;
    float hf = (float)hh;
    _Float16 mm = (_Float16)((v - hf) * 4096.0f);
    size_t pb = plidx16(b, n, o);
    ph[pb] = __builtin_bit_cast(unsigned short, hh);
    pm[pb] = __builtin_bit_cast(unsigned short, mm);
  }
}

// ascending bitonic sort of 32 floats as elements (2l, 2l+1) across 16 lanes
__device__ __forceinline__ void bitonic32f(float& v0, float& v1, int l15)
{
  #pragma unroll
  for (int k = 2; k <= 32; k <<= 1) {
    #pragma unroll
    for (int j = k >> 1; j >= 1; j >>= 1) {
      bool dirup = ((2 * l15) & k) == 0;
      if (j >= 2) {
        int lj = j >> 1;
        float p0 = __shfl_xor(v0, lj, 16);
        float p1 = __shfl_xor(v1, lj, 16);
        bool lower = (l15 & lj) == 0;
        bool keepmin = (dirup == lower);
        v0 = keepmin ? fminf(v0, p0) : fmaxf(v0, p0);
        v1 = keepmin ? fminf(v1, p1) : fmaxf(v1, p1);
      } else {
        float lo = fminf(v0, v1), hi = fmaxf(v0, v1);
        v0 = dirup ? lo : hi;
        v1 = dirup ? hi : lo;
      }
    }
  }
}

// ascending bitonic sort of 64 u64 keys as elements (2l, 2l+1) across 32 lanes
__device__ __forceinline__ void bitonic64k(u64& v0, u64& v1, int l31)
{
  #pragma unroll
  for (int k = 2; k <= 64; k <<= 1) {
    #pragma unroll
    for (int j = k >> 1; j >= 1; j >>= 1) {
      bool dirup = ((2 * l31) & k) == 0;
      if (j >= 2) {
        int lj = j >> 1;
        u64 p0 = __shfl_xor(v0, lj, 32);
        u64 p1 = __shfl_xor(v1, lj, 32);
        bool lower = (l31 & lj) == 0;
        bool keepmin = (dirup == lower);
        u64 a0 = v0 < p0 ? v0 : p0, b0 = v0 < p0 ? p0 : v0;
        u64 a1 = v1 < p1 ? v1 : p1, b1 = v1 < p1 ? p1 : v1;
        v0 = keepmin ? a0 : b0;
        v1 = keepmin ? a1 : b1;
      } else {
        u64 lo = v0 < v1 ? v0 : v1, hi = v0 < v1 ? v1 : v0;
        v0 = dirup ? lo : hi;
        v1 = dirup ? hi : lo;
      }
    }
  }
}

// monotone u64 key: (order-preserving f32 bits << 16) | col (col < 4096)
__device__ __forceinline__ u64 mkkey(float d, unsigned short idx)
{
  unsigned ub = __float_as_uint(d);
  unsigned mono = ub ^ (0x80000000u | (unsigned)((int)ub >> 31));
  return ((u64)mono << 16) | idx;
}

// ---------------- knn pass A: fp16-hi min2 pool -> tau per row ----------------
__global__ void __launch_bounds__(256) knn_a_kernel(
    const ushort_t* __restrict__ ph,
    const float* __restrict__ sq, float* __restrict__ tauG)
{
  __shared__ float sqs[1024];      // this slice's sq (4 KB -> LDS-free occupancy)

  const int t = threadIdx.x;
  const int lane = t & 63;
  const int l15 = lane & 15;
  const int q = lane >> 4;
  const int blk = blockIdx.x;
  const int slice = blk & 3;
  const int g = (blk >> 2) & 63;
  const int b = blk >> 8;
  const int wv = t >> 6;
  const int n0w = (g * 4 + wv) * 16;

  const float* __restrict__ sqb = sq + (size_t)b * NN;
  const int laneoff = q * 128 + l15 * 8;

  #pragma unroll
  for (int i = 0; i < 4; ++i)
    sqs[t + i * 256] = sqb[slice * 1024 + t + i * 256];
  __syncthreads();

  const bool hasdiag = ((n0w >> 10) == slice);
  const int dmc = (n0w & 1023) >> 5;

  // resident A fragments, NEGATED: MFMA accumulates sq_m - y_n.y_m (C = sq_m)
  half8 Ah[2];
  {
    size_t abase = ((size_t)b * 256 + (n0w >> 4)) * 1024 + laneoff;
    #pragma unroll
    for (int s = 0; s < 2; ++s) {
      Ah[s] = *(const half8*)(ph + abase + s * 512);
      uintx4 uh = __builtin_bit_cast(uintx4, Ah[s]); uh ^= 0x80008000u;
      Ah[s] = __builtin_bit_cast(half8, uh);
    }
  }

  // per-lane min2 per row over 32 chunks (ti-merged candidates)
  float m1[4], m2[4];
  #pragma unroll
  for (int r = 0; r < 4; ++r) { m1[r] = FLT_MAX; m2[r] = FLT_MAX; }

  for (int mc = 0; mc < 32; ++mc) {
    const int m0 = slice * 1024 + mc * 32;
    size_t mbase = ((size_t)b * 256 + (m0 >> 4)) * 1024 + laneoff;
    float sv0 = sqs[mc * 32 + l15];
    float sv1 = sqs[mc * 32 + 16 + l15];
    floatx4 a1[2];
    #pragma unroll
    for (int e = 0; e < 4; ++e) { a1[0][e] = sv0; a1[1][e] = sv1; }
    #pragma unroll
    for (int ti = 0; ti < 2; ++ti) {
      #pragma unroll
      for (int s = 0; s < 2; ++s) {
        half8 Bh = *(const half8*)(ph + mbase + ti * 1024 + s * 512);
        a1[ti] = __builtin_amdgcn_mfma_f32_16x16x32_f16(Ah[s], Bh, a1[ti], 0, 0, 0);
      }
    }
    if (hasdiag && mc == dmc) {
      #pragma unroll
      for (int ti = 0; ti < 2; ++ti) {
        int mcol = m0 + 16 * ti + l15;
        #pragma unroll
        for (int r = 0; r < 4; ++r)
          if (mcol == n0w + 4 * q + r) a1[ti][r] = FLT_MAX;
      }
    }
    #pragma unroll
    for (int r = 0; r < 4; ++r) {
      float c = fminf(a1[0][r], a1[1][r]);
      m2[r] = __builtin_amdgcn_fmed3f(c, m1[r], m2[r]);  // min2 update
      m1[r] = fminf(m1[r], c);
    }
  }

  // tau_r = 20th of 32-pool + PAD; element 19 = (lane 9, reg 1)
  float* trow = tauG + ((size_t)(b * SS + slice)) * NN + n0w;
  #pragma unroll
  for (int r = 0; r < 4; ++r) {
    float v0 = m1[r], v1 = m2[r];
    bitonic32f(v0, v1, l15);
    if (l15 == 9) trow[4 * q + r] = v1 + PAD;
  }
}

// ---------------- knn pass B: exact recompute, filter, sort, emit ----------------
__global__ void __launch_bounds__(256) knn_b_kernel(
    const ushort_t* __restrict__ ph, const ushort_t* __restrict__ pm,
    const float* __restrict__ sq, const float* __restrict__ tauG,
    u64* __restrict__ keys2)
{
  __shared__ float    bufd[4][16][CAP];   // 16384 B
  __shared__ ushort_t bufi[4][16][CAP];   //  8192 B
  __shared__ int scnt[4][16];

  const int t = threadIdx.x;
  const int lane = t & 63;
  const int l15 = lane & 15;
  const int q = lane >> 4;
  const int wv = t >> 6;
  const int blk = blockIdx.x;
  const int slice = blk & 3;
  const int g = (blk >> 2) & 63;
  const int b = blk >> 8;
  const int n0w = (g * 4 + wv) * 16;

  const float* __restrict__ sqb = sq + (size_t)b * NN;
  const float MS = 2.44140625e-4f;   // 2^-12
  const int laneoff = q * 128 + l15 * 8;

  const bool hasdiag = ((n0w >> 10) == slice);
  const int dmc = (n0w & 1023) >> 5;

  half8 Ah[2], Am[2];
  {
    size_t abase = ((size_t)b * 256 + (n0w >> 4)) * 1024 + laneoff;
    #pragma unroll
    for (int s = 0; s < 2; ++s) {
      Ah[s] = *(const half8*)(ph + abase + s * 512);
      Am[s] = *(const half8*)(pm + abase + s * 512);
      uintx4 uh = __builtin_bit_cast(uintx4, Ah[s]); uh ^= 0x80008000u;
      uintx4 um = __builtin_bit_cast(uintx4, Am[s]); um ^= 0x80008000u;
      Ah[s] = __builtin_bit_cast(half8, uh);
      Am[s] = __builtin_bit_cast(half8, um);
    }
  }

  // per-row padded tau from pass A
  const float* trow = tauG + ((size_t)(b * SS + slice)) * NN + n0w;
  float taupad[4];
  #pragma unroll
  for (int r = 0; r < 4; ++r) taupad[r] = trow[4 * q + r];

  int cnt[4];
  #pragma unroll
  for (int r = 0; r < 4; ++r) cnt[r] = 0;

  for (int mc = 0; mc < 32; ++mc) {
    const int m0 = slice * 1024 + mc * 32;
    size_t mbase = ((size_t)b * 256 + (m0 >> 4)) * 1024 + laneoff;
    float sv0 = sqb[m0 + l15];
    float sv1 = sqb[m0 + 16 + l15];
    floatx4 a1[2], a2[2];
    #pragma unroll
    for (int e = 0; e < 4; ++e) {
      a1[0][e] = sv0; a1[1][e] = sv1;
      a2[0][e] = 0.f; a2[1][e] = 0.f;
    }
    #pragma unroll
    for (int ti = 0; ti < 2; ++ti) {
      #pragma unroll
      for (int s = 0; s < 2; ++s) {
        half8 Bh = *(const half8*)(ph + mbase + ti * 1024 + s * 512);
        half8 Bm = *(const half8*)(pm + mbase + ti * 1024 + s * 512);
        a1[ti] = __builtin_amdgcn_mfma_f32_16x16x32_f16(Ah[s], Bh, a1[ti], 0, 0, 0);
        a2[ti] = __builtin_amdgcn_mfma_f32_16x16x32_f16(Am[s], Bh, a2[ti], 0, 0, 0);
        a2[ti] = __builtin_amdgcn_mfma_f32_16x16x32_f16(Ah[s], Bm, a2[ti], 0, 0, 0);
      }
    }
    #pragma unroll
    for (int ti = 0; ti < 2; ++ti)
      #pragma unroll
      for (int r = 0; r < 4; ++r)
        a1[ti][r] = __builtin_fmaf(MS, a2[ti][r], a1[ti][r]);
    if (hasdiag && mc == dmc) {
      #pragma unroll
      for (int ti = 0; ti < 2; ++ti) {
        int mcol = m0 + 16 * ti + l15;
        #pragma unroll
        for (int r = 0; r < 4; ++r)
          if (mcol == n0w + 4 * q + r) a1[ti][r] = FLT_MAX;
      }
    }
    #pragma unroll
    for (int ti = 0; ti < 2; ++ti) {
      int mcol = m0 + 16 * ti + l15;
      #pragma unroll
      for (int r = 0; r < 4; ++r) {
        bool ok = a1[ti][r] <= taupad[r];
        unsigned long long bal = __ballot(ok);
        unsigned mh = (unsigned)((bal >> (q * 16)) & 0xFFFFull);
        int pre = __popc(mh & ((1u << l15) - 1u));
        int slot = cnt[r] + pre;
        if (ok && slot < CAP) {
          bufd[wv][4 * q + r][slot] = a1[ti][r];
          bufi[wv][4 * q + r][slot] = (ushort_t)mcol;
        }
        cnt[r] += __popc(mh);
      }
    }
  }

  if (l15 == 0) {
    #pragma unroll
    for (int r = 0; r < 4; ++r) scnt[wv][4 * q + r] = cnt[r];
  }
  __builtin_amdgcn_s_waitcnt(0);   // drain LDS writes (same-wave read below)

  // final: per half-wave, sort 8 rows' survivors, emit sorted top-20
  const int l31 = t & 31;
  const int hfw = (t >> 5) & 1;
  #pragma unroll
  for (int i = 0; i < 8; ++i) {
    int rloc = hfw * 8 + i;
    int c = scnt[wv][rloc];
    c = c < CAP ? c : CAP;
    floatx2  dv = *(const floatx2*)&bufd[wv][rloc][2 * l31];
    ushortx2 iv = *(const ushortx2*)&bufi[wv][rloc][2 * l31];
    u64 k0 = (2 * l31     < c) ? mkkey(dv[0], iv[0]) : ~0ull;
    u64 k1 = (2 * l31 + 1 < c) ? mkkey(dv[1], iv[1]) : ~0ull;
    bitonic64k(k0, k1, l31);
    u64 a = __shfl(k0, l31 >> 1, 32);
    u64 b2 = __shfl(k1, l31 >> 1, 32);
    u64 kv = (l31 & 1) ? b2 : a;
    if (l31 < KK) {
      size_t rowg = ((size_t)b * NN + n0w + rloc) * SS + slice;
      keys2[rowg * KK + l31] = kv;
    }
  }
}

// ---------------- merge four sorted 20-key lists per row ----------------
__global__ void __launch_bounds__(256) merge_kernel(
    const u64* __restrict__ keys2, int* __restrict__ idxOut)
{
  int row = blockIdx.x * 256 + threadIdx.x;   // 0..32767
  if (row >= BB * NN) return;
  u64 h[SS]; int p[SS];
  #pragma unroll
  for (int s = 0; s < SS; ++s) {
    p[s] = 0;
    h[s] = keys2[((size_t)row * SS + s) * KK];
  }
  int* op = idxOut + (size_t)row * KK;
  #pragma unroll
  for (int q = 0; q < KK; ++q) {
    int bs = 0;
    u64 bv = h[0];
    #pragma unroll
    for (int s = 1; s < SS; ++s) { if (h[s] < bv) { bv = h[s]; bs = s; } }
    op[q] = (int)(bv & 0xFFFFull);            // col in low 16 bits
    p[bs]++;
    h[bs] = (p[bs] < KK) ? keys2[((size_t)row * SS + bs) * KK + p[bs]] : ~0ull;
  }
}

// ---------------- gather: out[b,o,n] = P + max_j Q[nbr_j] ----------------
__global__ void __launch_bounds__(256) gather_kernel(
    const float* __restrict__ x, const float* __restrict__ W,
    const float* __restrict__ bias,
    const float* __restrict__ Q, const int* __restrict__ idxIn,
    float* __restrict__ out)
{
  __shared__ float xs[64][65];
  __shared__ float wp[64][65];
  __shared__ float ot[64][65];
  __shared__ float bs[64];
  int t = threadIdx.x;
  int b = blockIdx.x >> 6;
  int n0 = (blockIdx.x & 63) << 6;
  const float* xb = x + (size_t)b * FF * NN;

  int nl0 = t & 63, fq = t >> 6;
  #pragma unroll
  for (int i = 0; i < 16; ++i) {
    int f = fq + i * 4;
    xs[f][nl0] = xb[(size_t)f * NN + n0 + nl0];
  }
  #pragma unroll
  for (int i = 0; i < 16; ++i) {
    int id = i * 256 + t;            // 0..4095
    int o = id >> 6, f = id & 63;
    wp[o][f] = W[o * 128 + f] - W[o * 128 + 64 + f];   // W1 - W2
  }
  if (t < 64) bs[t] = bias[t];
  __syncthreads();

  int o = t & 63, g = t >> 6;
  for (int i = 0; i < 16; ++i) {
    int nl = g + i * 4;
    int n = n0 + nl;
    float p = bs[o];
    #pragma unroll
    for (int f = 0; f < FF; ++f) p += wp[o][f] * xs[f][nl];
    const int* ip = idxIn + ((size_t)b * NN + n) * KK;
    float m = -FLT_MAX;
    #pragma unroll
    for (int j = 0; j < KK; ++j) {
      int nb = ip[j];                                   // wave-uniform
      m = fmaxf(m, Q[((size_t)b * NN + nb) * FF + o]);  // 256B coalesced
    }
    ot[nl][o] = p + m;
  }
  __syncthreads();
  for (int i = 0; i < 16; ++i) {
    int o2 = g + i * 4;
    int nl = t & 63;
    out[((size_t)b * FF + o2) * NN + n0 + nl] = ot[nl][o2];
  }
}

extern "C" void kernel_launch(void* const* d_in, const int* in_sizes, int n_in,
                              void* d_out, int out_size, void* d_ws, size_t ws_size,
                              hipStream_t stream)
{
  const float* x    = (const float*)d_in[0];
  const float* W    = (const float*)d_in[1];
  const float* bias = (const float*)d_in[2];
  float* out = (float*)d_out;

  int*   idxb = (int*)d_ws;                               // 8*4096*20 ints
  float* sq   = (float*)(idxb + (size_t)BB * NN * KK);    // 8*4096
  float* Q    = sq + (size_t)BB * NN;                     // 8*4096*64
  ushort_t* ph = (ushort_t*)(Q + (size_t)BB * NN * FF);   // 8*4096*64 each
  ushort_t* pm = ph + (size_t)BB * NN * FF;
  u64*   keys2 = (u64*)(pm + (size_t)BB * NN * FF);       // 8*4096*4*20
  // tau overlays idxb (8*4096*4 floats = 512 KB <= idxb's 2.5 MB);
  // lifetime: written by knn_a, read by knn_b, dead before merge writes idxb.
  float* tauG = (float*)idxb;

  prep_kernel<<<BB * (NN / 64), 256, 0, stream>>>(x, W, sq, Q, ph, pm);
  knn_a_kernel<<<BB * 64 * SS, 256, 0, stream>>>(ph, sq, tauG);
  knn_b_kernel<<<BB * 64 * SS, 256, 0, stream>>>(ph, pm, sq, tauG, keys2);
  merge_kernel<<<(BB * NN + 255) / 256, 256, 0, stream>>>(keys2, idxb);
  gather_kernel<<<BB * (NN / 64), 256, 0, stream>>>(x, W, bias, Q, idxb, out);
}

// Round 6
// 280.113 us; speedup vs baseline: 1.0430x; 1.0212x over previous
//
#include <hip/hip_runtime.h>
#include <hip/hip_bf16.h>
#include <float.h>

// EdgeConv (fp32 I/O):
//   out[b,o,n] = P[b,n,o] + max_{j<20} Q[b, idx[b,n,j], o]
//   P = (W1-W2)^T x + b ; Q = W2^T x
//   knn: top-20 smallest of score[m] = sq[m] - 2*x_n.x_m  (m != n)
// Round 20 (consolidate): R5 attribution: passA~43us, passB~140us, split
// overhead ~6us; passB's dominant VALU term is ballot bookkeeping
// (~10 VALU x 8 cands/chunk). Changes:
//  - re-fuse passes (tau in regs, A-frags loaded once)
//  - wave-uniform `if (bal)` skip of empty survivor groups (~20% of groups)
//  - PAD 1.0 -> 0.3 (passB filters on EXACT values; need only PAD >= eps,
//    eps = fp16-hi distance err <= MS*|a2| ~= 0.125; 2.4x margin)
// tau = 20th of 32-pool (+PAD). CAP 64. Ballot compaction (R1-proven).
// Planes hold y = sqrt(2)*x fp16x2, tiled [b][n>>4][k>>3][n&15][k&7].

#define BB 8
#define FF 64
#define NN 4096
#define KK 20
#define CAP 64
#define SS 4
#define PAD 0.3f

typedef unsigned short ushort_t;
typedef unsigned long long u64;
typedef __attribute__((ext_vector_type(8))) _Float16 half8;
typedef __attribute__((ext_vector_type(4))) float floatx4;
typedef __attribute__((ext_vector_type(2))) float floatx2;
typedef __attribute__((ext_vector_type(2))) unsigned short ushortx2;
typedef __attribute__((ext_vector_type(4))) unsigned int uintx4;

// plane flat index (shorts): [b][n>>4][k>>3][n&15][k&7]
__device__ __forceinline__ size_t plidx16(int b, int n, int k) {
  return ((size_t)b * 256 + (n >> 4)) * 1024 + (size_t)(k >> 3) * 128 + (size_t)(n & 15) * 8 + (k & 7);
}

// ---------------- prep: sq, Q, fp16x2 planes of y = sqrt(2)*x ----------------
__global__ void __launch_bounds__(256) prep_kernel(
    const float* __restrict__ x, const float* __restrict__ W,
    float* __restrict__ sq, float* __restrict__ Q,
    ushort_t* __restrict__ ph, ushort_t* __restrict__ pm)
{
  __shared__ float xs[64][65];
  __shared__ float w2[64][65];
  int t = threadIdx.x;
  int b = blockIdx.x >> 6;
  int n0 = (blockIdx.x & 63) << 6;
  const float* xb = x + (size_t)b * FF * NN;

  int nl = t & 63, fq = t >> 6;
  #pragma unroll
  for (int i = 0; i < 16; ++i) {
    int f = fq + i * 4;
    xs[f][nl] = xb[(size_t)f * NN + n0 + nl];
  }
  #pragma unroll
  for (int i = 0; i < 16; ++i) {
    int id = i * 256 + t;            // 0..4095
    int o = id >> 6, f = id & 63;
    w2[o][f] = W[o * 128 + 64 + f];  // W2
  }
  __syncthreads();

  if (t < 64) {
    float s = 0.f;
    #pragma unroll
    for (int f = 0; f < FF; ++f) { float v = xs[f][t]; s += v * v; }
    sq[b * NN + n0 + t] = s;
  }
  int o = t & 63, g = t >> 6;
  for (int i = 0; i < 16; ++i) {
    int r = g + i * 4;
    int n = n0 + r;
    float acc = 0.f;
    #pragma unroll
    for (int f = 0; f < FF; ++f) acc += w2[o][f] * xs[f][r];
    Q[((size_t)b * NN + n) * FF + o] = acc;

    // fp16x2 split of y = sqrt(2)*x: y = h + m*2^-12 (m stored pre-scaled by 4096)
    float v = xs[o][r] * 1.41421356237309515f;
    _Float16 hh = (_Float16)v;
    float hf = (float)hh;
    _Float16 mm = (_Float16)((v - hf) * 4096.0f);
    size_t pb = plidx16(b, n, o);
    ph[pb] = __builtin_bit_cast(unsigned short, hh);
    pm[pb] = __builtin_bit_cast(unsigned short, mm);
  }
}

// ascending bitonic sort of 32 floats as elements (2l, 2l+1) across 16 lanes
__device__ __forceinline__ void bitonic32f(float& v0, float& v1, int l15)
{
  #pragma unroll
  for (int k = 2; k <= 32; k <<= 1) {
    #pragma unroll
    for (int j = k >> 1; j >= 1; j >>= 1) {
      bool dirup = ((2 * l15) & k) == 0;
      if (j >= 2) {
        int lj = j >> 1;
        float p0 = __shfl_xor(v0, lj, 16);
        float p1 = __shfl_xor(v1, lj, 16);
        bool lower = (l15 & lj) == 0;
        bool keepmin = (dirup == lower);
        v0 = keepmin ? fminf(v0, p0) : fmaxf(v0, p0);
        v1 = keepmin ? fminf(v1, p1) : fmaxf(v1, p1);
      } else {
        float lo = fminf(v0, v1), hi = fmaxf(v0, v1);
        v0 = dirup ? lo : hi;
        v1 = dirup ? hi : lo;
      }
    }
  }
}

// ascending bitonic sort of 64 u64 keys as elements (2l, 2l+1) across 32 lanes
__device__ __forceinline__ void bitonic64k(u64& v0, u64& v1, int l31)
{
  #pragma unroll
  for (int k = 2; k <= 64; k <<= 1) {
    #pragma unroll
    for (int j = k >> 1; j >= 1; j >>= 1) {
      bool dirup = ((2 * l31) & k) == 0;
      if (j >= 2) {
        int lj = j >> 1;
        u64 p0 = __shfl_xor(v0, lj, 32);
        u64 p1 = __shfl_xor(v1, lj, 32);
        bool lower = (l31 & lj) == 0;
        bool keepmin = (dirup == lower);
        u64 a0 = v0 < p0 ? v0 : p0, b0 = v0 < p0 ? p0 : v0;
        u64 a1 = v1 < p1 ? v1 : p1, b1 = v1 < p1 ? p1 : v1;
        v0 = keepmin ? a0 : b0;
        v1 = keepmin ? a1 : b1;
      } else {
        u64 lo = v0 < v1 ? v0 : v1, hi = v0 < v1 ? v1 : v0;
        v0 = dirup ? lo : hi;
        v1 = dirup ? hi : lo;
      }
    }
  }
}

// monotone u64 key: (order-preserving f32 bits << 16) | col (col < 4096)
__device__ __forceinline__ u64 mkkey(float d, unsigned short idx)
{
  unsigned ub = __float_as_uint(d);
  unsigned mono = ub ^ (0x80000000u | (unsigned)((int)ub >> 31));
  return ((u64)mono << 16) | idx;
}

// ---------------- knn: two-pass threshold filter, 16 rows/wave ----------------
__global__ void __launch_bounds__(256) knn_kernel(
    const ushort_t* __restrict__ ph, const ushort_t* __restrict__ pm,
    const float* __restrict__ sq, u64* __restrict__ keys2)
{
  __shared__ float    bufd[4][16][CAP];   // 16384 B
  __shared__ ushort_t bufi[4][16][CAP];   //  8192 B
  __shared__ int scnt[4][16];

  const int t = threadIdx.x;
  const int lane = t & 63;
  const int l15 = lane & 15;
  const int q = lane >> 4;          // quarter 0..3 (C rows 4q..4q+3)
  const int wv = t >> 6;
  const int blk = blockIdx.x;
  const int slice = blk & 3;
  const int g = (blk >> 2) & 63;    // 64 groups per batch
  const int b = blk >> 8;
  const int n0w = (g * 4 + wv) * 16;   // this wave's 16-row tile

  const float* __restrict__ sqb = sq + (size_t)b * NN;
  const float MS = 2.44140625e-4f;   // 2^-12
  const int laneoff = q * 128 + l15 * 8;

  // diagonal (self) lives in exactly one chunk of one slice for this wave
  const bool hasdiag = ((n0w >> 10) == slice);
  const int dmc = (n0w & 1023) >> 5;

  // resident A fragments: row = l15, k = 32s + 8q + e ; NEGATED so the MFMA
  // accumulates  sq_m - y_n.y_m  directly (C-init = sq_m).
  half8 Ah[2], Am[2];
  {
    size_t abase = ((size_t)b * 256 + (n0w >> 4)) * 1024 + laneoff;
    #pragma unroll
    for (int s = 0; s < 2; ++s) {
      Ah[s] = *(const half8*)(ph + abase + s * 512);
      Am[s] = *(const half8*)(pm + abase + s * 512);
      uintx4 uh = __builtin_bit_cast(uintx4, Ah[s]); uh ^= 0x80008000u;
      uintx4 um = __builtin_bit_cast(uintx4, Am[s]); um ^= 0x80008000u;
      Ah[s] = __builtin_bit_cast(half8, uh);
      Am[s] = __builtin_bit_cast(half8, um);
    }
  }

  // -------- pass A (fp16-hi only): per-lane min2 per row over 32 chunks --------
  // pool = 32 values (16 lanes x best-2 of each lane's ti-merged candidates);
  // 20 smallest pool entries are distinct candidates -> >=20 cands <= tau.
  float m1[4], m2[4];
  #pragma unroll
  for (int r = 0; r < 4; ++r) { m1[r] = FLT_MAX; m2[r] = FLT_MAX; }

  for (int mc = 0; mc < 32; ++mc) {
    const int m0 = slice * 1024 + mc * 32;
    size_t mbase = ((size_t)b * 256 + (m0 >> 4)) * 1024 + laneoff;
    float sv0 = sqb[m0 + l15];
    float sv1 = sqb[m0 + 16 + l15];
    floatx4 a1[2];
    #pragma unroll
    for (int e = 0; e < 4; ++e) { a1[0][e] = sv0; a1[1][e] = sv1; }
    #pragma unroll
    for (int ti = 0; ti < 2; ++ti) {
      #pragma unroll
      for (int s = 0; s < 2; ++s) {
        half8 Bh = *(const half8*)(ph + mbase + ti * 1024 + s * 512);
        a1[ti] = __builtin_amdgcn_mfma_f32_16x16x32_f16(Ah[s], Bh, a1[ti], 0, 0, 0);
      }
    }
    if (hasdiag && mc == dmc) {
      #pragma unroll
      for (int ti = 0; ti < 2; ++ti) {
        int mcol = m0 + 16 * ti + l15;
        #pragma unroll
        for (int r = 0; r < 4; ++r)
          if (mcol == n0w + 4 * q + r) a1[ti][r] = FLT_MAX;
      }
    }
    #pragma unroll
    for (int r = 0; r < 4; ++r) {
      float c = fminf(a1[0][r], a1[1][r]);
      m2[r] = __builtin_amdgcn_fmed3f(c, m1[r], m2[r]);  // min2 update
      m1[r] = fminf(m1[r], c);
    }
  }

  // tau_r = 20th of 32-pool (approx) + PAD; PAD >= fp16-hi distance error
  float taupad[4];
  #pragma unroll
  for (int r = 0; r < 4; ++r) {
    float v0 = m1[r], v1 = m2[r];
    bitonic32f(v0, v1, l15);
    taupad[r] = __shfl(v1, 9, 16) + PAD;   // element 19 = lane 9, reg 1
  }

  // -------- pass B: exact fp16x2 recompute, ballot-compact into LDS --------
  int cnt[4];
  #pragma unroll
  for (int r = 0; r < 4; ++r) cnt[r] = 0;

  for (int mc = 0; mc < 32; ++mc) {
    const int m0 = slice * 1024 + mc * 32;
    size_t mbase = ((size_t)b * 256 + (m0 >> 4)) * 1024 + laneoff;
    float sv0 = sqb[m0 + l15];
    float sv1 = sqb[m0 + 16 + l15];
    floatx4 a1[2], a2[2];
    #pragma unroll
    for (int e = 0; e < 4; ++e) {
      a1[0][e] = sv0; a1[1][e] = sv1;
      a2[0][e] = 0.f; a2[1][e] = 0.f;
    }
    #pragma unroll
    for (int ti = 0; ti < 2; ++ti) {
      #pragma unroll
      for (int s = 0; s < 2; ++s) {
        half8 Bh = *(const half8*)(ph + mbase + ti * 1024 + s * 512);
        half8 Bm = *(const half8*)(pm + mbase + ti * 1024 + s * 512);
        a1[ti] = __builtin_amdgcn_mfma_f32_16x16x32_f16(Ah[s], Bh, a1[ti], 0, 0, 0);
        a2[ti] = __builtin_amdgcn_mfma_f32_16x16x32_f16(Am[s], Bh, a2[ti], 0, 0, 0);
        a2[ti] = __builtin_amdgcn_mfma_f32_16x16x32_f16(Ah[s], Bm, a2[ti], 0, 0, 0);
      }
    }
    // exact cand = a1 + MS*a2, in place
    #pragma unroll
    for (int ti = 0; ti < 2; ++ti)
      #pragma unroll
      for (int r = 0; r < 4; ++r)
        a1[ti][r] = __builtin_fmaf(MS, a2[ti][r], a1[ti][r]);
    if (hasdiag && mc == dmc) {
      #pragma unroll
      for (int ti = 0; ti < 2; ++ti) {
        int mcol = m0 + 16 * ti + l15;
        #pragma unroll
        for (int r = 0; r < 4; ++r)
          if (mcol == n0w + 4 * q + r) a1[ti][r] = FLT_MAX;
      }
    }
    #pragma unroll
    for (int ti = 0; ti < 2; ++ti) {
      int mcol = m0 + 16 * ti + l15;
      #pragma unroll
      for (int r = 0; r < 4; ++r) {
        bool ok = a1[ti][r] <= taupad[r];
        unsigned long long bal = __ballot(ok);
        if (bal) {                       // wave-uniform skip of empty groups
          unsigned mh = (unsigned)((bal >> (q * 16)) & 0xFFFFull);
          int pre = __popc(mh & ((1u << l15) - 1u));
          int slot = cnt[r] + pre;
          if (ok && slot < CAP) {
            bufd[wv][4 * q + r][slot] = a1[ti][r];
            bufi[wv][4 * q + r][slot] = (ushort_t)mcol;
          }
          cnt[r] += __popc(mh);
        }
      }
    }
  }

  if (l15 == 0) {
    #pragma unroll
    for (int r = 0; r < 4; ++r) scnt[wv][4 * q + r] = cnt[r];
  }
  __builtin_amdgcn_s_waitcnt(0);   // drain LDS writes (same-wave read below)

  // -------- final: per half-wave, sort 8 rows' survivors, emit sorted top-20 --------
  const int l31 = t & 31;
  const int hfw = (t >> 5) & 1;
  #pragma unroll
  for (int i = 0; i < 8; ++i) {
    int rloc = hfw * 8 + i;
    int c = scnt[wv][rloc];
    c = c < CAP ? c : CAP;
    floatx2  dv = *(const floatx2*)&bufd[wv][rloc][2 * l31];
    ushortx2 iv = *(const ushortx2*)&bufi[wv][rloc][2 * l31];
    u64 k0 = (2 * l31     < c) ? mkkey(dv[0], iv[0]) : ~0ull;
    u64 k1 = (2 * l31 + 1 < c) ? mkkey(dv[1], iv[1]) : ~0ull;
    bitonic64k(k0, k1, l31);
    u64 a = __shfl(k0, l31 >> 1, 32);
    u64 b2 = __shfl(k1, l31 >> 1, 32);
    u64 kv = (l31 & 1) ? b2 : a;              // element l31 of sorted order
    if (l31 < KK) {
      size_t rowg = ((size_t)b * NN + n0w + rloc) * SS + slice;
      keys2[rowg * KK + l31] = kv;
    }
  }
}

// ---------------- merge four sorted 20-key lists per row ----------------
__global__ void __launch_bounds__(256) merge_kernel(
    const u64* __restrict__ keys2, int* __restrict__ idxOut)
{
  int row = blockIdx.x * 256 + threadIdx.x;   // 0..32767
  if (row >= BB * NN) return;
  u64 h[SS]; int p[SS];
  #pragma unroll
  for (int s = 0; s < SS; ++s) {
    p[s] = 0;
    h[s] = keys2[((size_t)row * SS + s) * KK];
  }
  int* op = idxOut + (size_t)row * KK;
  #pragma unroll
  for (int q = 0; q < KK; ++q) {
    int bs = 0;
    u64 bv = h[0];
    #pragma unroll
    for (int s = 1; s < SS; ++s) { if (h[s] < bv) { bv = h[s]; bs = s; } }
    op[q] = (int)(bv & 0xFFFFull);            // col in low 16 bits
    p[bs]++;
    h[bs] = (p[bs] < KK) ? keys2[((size_t)row * SS + bs) * KK + p[bs]] : ~0ull;
  }
}

// ---------------- gather: out[b,o,n] = P + max_j Q[nbr_j] ----------------
__global__ void __launch_bounds__(256) gather_kernel(
    const float* __restrict__ x, const float* __restrict__ W,
    const float* __restrict__ bias,
    const float* __restrict__ Q, const int* __restrict__ idxIn,
    float* __restrict__ out)
{
  __shared__ float xs[64][65];
  __shared__ float wp[64][65];
  __shared__ float ot[64][65];
  __shared__ float bs[64];
  int t = threadIdx.x;
  int b = blockIdx.x >> 6;
  int n0 = (blockIdx.x & 63) << 6;
  const float* xb = x + (size_t)b * FF * NN;

  int nl0 = t & 63, fq = t >> 6;
  #pragma unroll
  for (int i = 0; i < 16; ++i) {
    int f = fq + i * 4;
    xs[f][nl0] = xb[(size_t)f * NN + n0 + nl0];
  }
  #pragma unroll
  for (int i = 0; i < 16; ++i) {
    int id = i * 256 + t;            // 0..4095
    int o = id >> 6, f = id & 63;
    wp[o][f] = W[o * 128 + f] - W[o * 128 + 64 + f];   // W1 - W2
  }
  if (t < 64) bs[t] = bias[t];
  __syncthreads();

  int o = t & 63, g = t >> 6;
  for (int i = 0; i < 16; ++i) {
    int nl = g + i * 4;
    int n = n0 + nl;
    float p = bs[o];
    #pragma unroll
    for (int f = 0; f < FF; ++f) p += wp[o][f] * xs[f][nl];
    const int* ip = idxIn + ((size_t)b * NN + n) * KK;
    float m = -FLT_MAX;
    #pragma unroll
    for (int j = 0; j < KK; ++j) {
      int nb = ip[j];                                   // wave-uniform
      m = fmaxf(m, Q[((size_t)b * NN + nb) * FF + o]);  // 256B coalesced
    }
    ot[nl][o] = p + m;
  }
  __syncthreads();
  for (int i = 0; i < 16; ++i) {
    int o2 = g + i * 4;
    int nl = t & 63;
    out[((size_t)b * FF + o2) * NN + n0 + nl] = ot[nl][o2];
  }
}

extern "C" void kernel_launch(void* const* d_in, const int* in_sizes, int n_in,
                              void* d_out, int out_size, void* d_ws, size_t ws_size,
                              hipStream_t stream)
{
  const float* x    = (const float*)d_in[0];
  const float* W    = (const float*)d_in[1];
  const float* bias = (const float*)d_in[2];
  float* out = (float*)d_out;

  int*   idxb = (int*)d_ws;                               // 8*4096*20
  float* sq   = (float*)(idxb + (size_t)BB * NN * KK);    // 8*4096
  float* Q    = sq + (size_t)BB * NN;                     // 8*4096*64
  ushort_t* ph = (ushort_t*)(Q + (size_t)BB * NN * FF);   // 8*4096*64 each
  ushort_t* pm = ph + (size_t)BB * NN * FF;
  u64*   keys2 = (u64*)(pm + (size_t)BB * NN * FF);       // 8*4096*4*20

  prep_kernel<<<BB * (NN / 64), 256, 0, stream>>>(x, W, sq, Q, ph, pm);
  knn_kernel<<<BB * 64 * SS, 256, 0, stream>>>(ph, pm, sq, keys2);   // 2048 blocks
  merge_kernel<<<(BB * NN + 255) / 256, 256, 0, stream>>>(keys2, idxb);
  gather_kernel<<<BB * (NN / 64), 256, 0, stream>>>(x, W, bias, Q, idxb, out);
}

// Round 7
// 263.739 us; speedup vs baseline: 1.1078x; 1.0621x over previous
//
#include <hip/hip_runtime.h>
#include <hip/hip_bf16.h>
#include <float.h>

// EdgeConv (fp32 I/O):
//   out[b,o,n] = P[b,n,o] + max_{j<20} Q[b, idx[b,n,j], o]
//   P = (W1-W2)^T x + b ; Q = W2^T x
//   knn: top-20 smallest of score[m] = sq[m] - 2*x_n.x_m  (m != n)
// Round 21 (structural): R6 confirmed filter-shaving exhausted (179us ==
// R1's 177). Remaining fixed per-wave costs (2 bitonic phases, tau pool,
// A-frag setup, emit) are paid per slice; merge exists only for slices.
// Change: SS 4 -> 2. 1024 blocks = 4/CU = 16 waves/CU (grid was binding,
// occupancy should RISE); wave-sorts/pool-sorts/merge/keys-traffic halve.
// Survivor margins per slice-row unchanged (~22 vs CAP 64, same as green
// R6). Also: walking-pointer addressing in both mc loops (const 4KB
// stride, imm offsets 1024/2048/3072B) instead of 64-bit recompute.
// tau = 20th of 32-pool (+PAD 0.3 >= fp16-hi err 0.125). Ballot compact.
// Planes hold y = sqrt(2)*x fp16x2, tiled [b][n>>4][k>>3][n&15][k&7].

#define BB 8
#define FF 64
#define NN 4096
#define KK 20
#define CAP 64
#define SS 2
#define PAD 0.3f

typedef unsigned short ushort_t;
typedef unsigned long long u64;
typedef __attribute__((ext_vector_type(8))) _Float16 half8;
typedef __attribute__((ext_vector_type(4))) float floatx4;
typedef __attribute__((ext_vector_type(2))) float floatx2;
typedef __attribute__((ext_vector_type(2))) unsigned short ushortx2;
typedef __attribute__((ext_vector_type(4))) unsigned int uintx4;

// plane flat index (shorts): [b][n>>4][k>>3][n&15][k&7]
__device__ __forceinline__ size_t plidx16(int b, int n, int k) {
  return ((size_t)b * 256 + (n >> 4)) * 1024 + (size_t)(k >> 3) * 128 + (size_t)(n & 15) * 8 + (k & 7);
}

// ---------------- prep: sq, Q, fp16x2 planes of y = sqrt(2)*x ----------------
__global__ void __launch_bounds__(256) prep_kernel(
    const float* __restrict__ x, const float* __restrict__ W,
    float* __restrict__ sq, float* __restrict__ Q,
    ushort_t* __restrict__ ph, ushort_t* __restrict__ pm)
{
  __shared__ float xs[64][65];
  __shared__ float w2[64][65];
  int t = threadIdx.x;
  int b = blockIdx.x >> 6;
  int n0 = (blockIdx.x & 63) << 6;
  const float* xb = x + (size_t)b * FF * NN;

  int nl = t & 63, fq = t >> 6;
  #pragma unroll
  for (int i = 0; i < 16; ++i) {
    int f = fq + i * 4;
    xs[f][nl] = xb[(size_t)f * NN + n0 + nl];
  }
  #pragma unroll
  for (int i = 0; i < 16; ++i) {
    int id = i * 256 + t;            // 0..4095
    int o = id >> 6, f = id & 63;
    w2[o][f] = W[o * 128 + 64 + f];  // W2
  }
  __syncthreads();

  if (t < 64) {
    float s = 0.f;
    #pragma unroll
    for (int f = 0; f < FF; ++f) { float v = xs[f][t]; s += v * v; }
    sq[b * NN + n0 + t] = s;
  }
  int o = t & 63, g = t >> 6;
  for (int i = 0; i < 16; ++i) {
    int r = g + i * 4;
    int n = n0 + r;
    float acc = 0.f;
    #pragma unroll
    for (int f = 0; f < FF; ++f) acc += w2[o][f] * xs[f][r];
    Q[((size_t)b * NN + n) * FF + o] = acc;

    // fp16x2 split of y = sqrt(2)*x: y = h + m*2^-12 (m stored pre-scaled by 4096)
    float v = xs[o][r] * 1.41421356237309515f;
    _Float16 hh = (_Float16)v;
    float hf = (float)hh;
    _Float16 mm = (_Float16)((v - hf) * 4096.0f);
    size_t pb = plidx16(b, n, o);
    ph[pb] = __builtin_bit_cast(unsigned short, hh);
    pm[pb] = __builtin_bit_cast(unsigned short, mm);
  }
}

// ascending bitonic sort of 32 floats as elements (2l, 2l+1) across 16 lanes
__device__ __forceinline__ void bitonic32f(float& v0, float& v1, int l15)
{
  #pragma unroll
  for (int k = 2; k <= 32; k <<= 1) {
    #pragma unroll
    for (int j = k >> 1; j >= 1; j >>= 1) {
      bool dirup = ((2 * l15) & k) == 0;
      if (j >= 2) {
        int lj = j >> 1;
        float p0 = __shfl_xor(v0, lj, 16);
        float p1 = __shfl_xor(v1, lj, 16);
        bool lower = (l15 & lj) == 0;
        bool keepmin = (dirup == lower);
        v0 = keepmin ? fminf(v0, p0) : fmaxf(v0, p0);
        v1 = keepmin ? fminf(v1, p1) : fmaxf(v1, p1);
      } else {
        float lo = fminf(v0, v1), hi = fmaxf(v0, v1);
        v0 = dirup ? lo : hi;
        v1 = dirup ? hi : lo;
      }
    }
  }
}

// ascending bitonic sort of 64 u64 keys as elements (2l, 2l+1) across 32 lanes
__device__ __forceinline__ void bitonic64k(u64& v0, u64& v1, int l31)
{
  #pragma unroll
  for (int k = 2; k <= 64; k <<= 1) {
    #pragma unroll
    for (int j = k >> 1; j >= 1; j >>= 1) {
      bool dirup = ((2 * l31) & k) == 0;
      if (j >= 2) {
        int lj = j >> 1;
        u64 p0 = __shfl_xor(v0, lj, 32);
        u64 p1 = __shfl_xor(v1, lj, 32);
        bool lower = (l31 & lj) == 0;
        bool keepmin = (dirup == lower);
        u64 a0 = v0 < p0 ? v0 : p0, b0 = v0 < p0 ? p0 : v0;
        u64 a1 = v1 < p1 ? v1 : p1, b1 = v1 < p1 ? p1 : v1;
        v0 = keepmin ? a0 : b0;
        v1 = keepmin ? a1 : b1;
      } else {
        u64 lo = v0 < v1 ? v0 : v1, hi = v0 < v1 ? v1 : v0;
        v0 = dirup ? lo : hi;
        v1 = dirup ? hi : lo;
      }
    }
  }
}

// monotone u64 key: (order-preserving f32 bits << 16) | col (col < 4096)
__device__ __forceinline__ u64 mkkey(float d, unsigned short idx)
{
  unsigned ub = __float_as_uint(d);
  unsigned mono = ub ^ (0x80000000u | (unsigned)((int)ub >> 31));
  return ((u64)mono << 16) | idx;
}

// ---------------- knn: two-pass threshold filter, 16 rows/wave ----------------
__global__ void __launch_bounds__(256) knn_kernel(
    const ushort_t* __restrict__ ph, const ushort_t* __restrict__ pm,
    const float* __restrict__ sq, u64* __restrict__ keys2)
{
  __shared__ float    bufd[4][16][CAP];   // 16384 B
  __shared__ ushort_t bufi[4][16][CAP];   //  8192 B
  __shared__ int scnt[4][16];

  const int t = threadIdx.x;
  const int lane = t & 63;
  const int l15 = lane & 15;
  const int q = lane >> 4;          // quarter 0..3 (C rows 4q..4q+3)
  const int wv = t >> 6;
  const int blk = blockIdx.x;
  const int slice = blk & 1;        // SS=2 half-slices of 2048 candidates
  const int g = (blk >> 1) & 63;    // 64 groups per batch
  const int b = blk >> 7;
  const int n0w = (g * 4 + wv) * 16;   // this wave's 16-row tile

  const float* __restrict__ sqb = sq + (size_t)b * NN;
  const float MS = 2.44140625e-4f;   // 2^-12
  const int laneoff = q * 128 + l15 * 8;

  // diagonal (self) lives in exactly one chunk of one slice for this wave
  const bool hasdiag = ((n0w >> 11) == slice);
  const int dmc = (n0w & 2047) >> 5;

  // resident A fragments: row = l15, k = 32s + 8q + e ; NEGATED so the MFMA
  // accumulates  sq_m - y_n.y_m  directly (C-init = sq_m).
  half8 Ah[2], Am[2];
  {
    size_t abase = ((size_t)b * 256 + (n0w >> 4)) * 1024 + laneoff;
    #pragma unroll
    for (int s = 0; s < 2; ++s) {
      Ah[s] = *(const half8*)(ph + abase + s * 512);
      Am[s] = *(const half8*)(pm + abase + s * 512);
      uintx4 uh = __builtin_bit_cast(uintx4, Ah[s]); uh ^= 0x80008000u;
      uintx4 um = __builtin_bit_cast(uintx4, Am[s]); um ^= 0x80008000u;
      Ah[s] = __builtin_bit_cast(half8, uh);
      Am[s] = __builtin_bit_cast(half8, um);
    }
  }

  // walking-pointer bases for this slice's B panel (const 2048-short stride)
  const size_t slbase = (size_t)b * 262144 + (size_t)slice * 131072 + laneoff;

  // -------- pass A (fp16-hi only): per-lane min2 per row over 64 chunks --------
  // pool = 32 values (16 lanes x best-2 of ti-merged per-chunk minima);
  // 20 smallest pool entries are distinct candidates -> >=20 cands <= tau.
  float m1[4], m2[4];
  #pragma unroll
  for (int r = 0; r < 4; ++r) { m1[r] = FLT_MAX; m2[r] = FLT_MAX; }

  {
    const ushort_t* pB = ph + slbase;
    const float* psq = sqb + slice * 2048 + l15;
    for (int mc = 0; mc < 64; ++mc) {
      float sv0 = psq[0];
      float sv1 = psq[16];
      floatx4 a1[2];
      #pragma unroll
      for (int e = 0; e < 4; ++e) { a1[0][e] = sv0; a1[1][e] = sv1; }
      #pragma unroll
      for (int ti = 0; ti < 2; ++ti) {
        #pragma unroll
        for (int s = 0; s < 2; ++s) {
          half8 Bh = *(const half8*)(pB + ti * 1024 + s * 512);
          a1[ti] = __builtin_amdgcn_mfma_f32_16x16x32_f16(Ah[s], Bh, a1[ti], 0, 0, 0);
        }
      }
      if (hasdiag && mc == dmc) {
        const int m0 = slice * 2048 + mc * 32;
        #pragma unroll
        for (int ti = 0; ti < 2; ++ti) {
          int mcol = m0 + 16 * ti + l15;
          #pragma unroll
          for (int r = 0; r < 4; ++r)
            if (mcol == n0w + 4 * q + r) a1[ti][r] = FLT_MAX;
        }
      }
      #pragma unroll
      for (int r = 0; r < 4; ++r) {
        float c = fminf(a1[0][r], a1[1][r]);
        m2[r] = __builtin_amdgcn_fmed3f(c, m1[r], m2[r]);  // min2 update
        m1[r] = fminf(m1[r], c);
      }
      pB += 2048;
      psq += 32;
    }
  }

  // tau_r = 20th of 32-pool (approx) + PAD; PAD >= fp16-hi distance error
  float taupad[4];
  #pragma unroll
  for (int r = 0; r < 4; ++r) {
    float v0 = m1[r], v1 = m2[r];
    bitonic32f(v0, v1, l15);
    taupad[r] = __shfl(v1, 9, 16) + PAD;   // element 19 = lane 9, reg 1
  }

  // -------- pass B: exact fp16x2 recompute, ballot-compact into LDS --------
  int cnt[4];
  #pragma unroll
  for (int r = 0; r < 4; ++r) cnt[r] = 0;

  {
    const ushort_t* pB = ph + slbase;
    const ushort_t* pM = pm + slbase;
    const float* psq = sqb + slice * 2048 + l15;
    for (int mc = 0; mc < 64; ++mc) {
      float sv0 = psq[0];
      float sv1 = psq[16];
      floatx4 a1[2], a2[2];
      #pragma unroll
      for (int e = 0; e < 4; ++e) {
        a1[0][e] = sv0; a1[1][e] = sv1;
        a2[0][e] = 0.f; a2[1][e] = 0.f;
      }
      #pragma unroll
      for (int ti = 0; ti < 2; ++ti) {
        #pragma unroll
        for (int s = 0; s < 2; ++s) {
          half8 Bh = *(const half8*)(pB + ti * 1024 + s * 512);
          half8 Bm = *(const half8*)(pM + ti * 1024 + s * 512);
          a1[ti] = __builtin_amdgcn_mfma_f32_16x16x32_f16(Ah[s], Bh, a1[ti], 0, 0, 0);
          a2[ti] = __builtin_amdgcn_mfma_f32_16x16x32_f16(Am[s], Bh, a2[ti], 0, 0, 0);
          a2[ti] = __builtin_amdgcn_mfma_f32_16x16x32_f16(Ah[s], Bm, a2[ti], 0, 0, 0);
        }
      }
      // exact cand = a1 + MS*a2, in place
      #pragma unroll
      for (int ti = 0; ti < 2; ++ti)
        #pragma unroll
        for (int r = 0; r < 4; ++r)
          a1[ti][r] = __builtin_fmaf(MS, a2[ti][r], a1[ti][r]);
      const int m0 = slice * 2048 + mc * 32;
      if (hasdiag && mc == dmc) {
        #pragma unroll
        for (int ti = 0; ti < 2; ++ti) {
          int mcol = m0 + 16 * ti + l15;
          #pragma unroll
          for (int r = 0; r < 4; ++r)
            if (mcol == n0w + 4 * q + r) a1[ti][r] = FLT_MAX;
        }
      }
      #pragma unroll
      for (int ti = 0; ti < 2; ++ti) {
        int mcol = m0 + 16 * ti + l15;
        #pragma unroll
        for (int r = 0; r < 4; ++r) {
          bool ok = a1[ti][r] <= taupad[r];
          unsigned long long bal = __ballot(ok);
          if (bal) {                       // wave-uniform skip of empty groups
            unsigned mh = (unsigned)((bal >> (q * 16)) & 0xFFFFull);
            int pre = __popc(mh & ((1u << l15) - 1u));
            int slot = cnt[r] + pre;
            if (ok && slot < CAP) {
              bufd[wv][4 * q + r][slot] = a1[ti][r];
              bufi[wv][4 * q + r][slot] = (ushort_t)mcol;
            }
            cnt[r] += __popc(mh);
          }
        }
      }
      pB += 2048;
      pM += 2048;
      psq += 32;
    }
  }

  if (l15 == 0) {
    #pragma unroll
    for (int r = 0; r < 4; ++r) scnt[wv][4 * q + r] = cnt[r];
  }
  __builtin_amdgcn_s_waitcnt(0);   // drain LDS writes (same-wave read below)

  // -------- final: per half-wave, sort 8 rows' survivors, emit sorted top-20 --------
  const int l31 = t & 31;
  const int hfw = (t >> 5) & 1;
  #pragma unroll
  for (int i = 0; i < 8; ++i) {
    int rloc = hfw * 8 + i;
    int c = scnt[wv][rloc];
    c = c < CAP ? c : CAP;
    floatx2  dv = *(const floatx2*)&bufd[wv][rloc][2 * l31];
    ushortx2 iv = *(const ushortx2*)&bufi[wv][rloc][2 * l31];
    u64 k0 = (2 * l31     < c) ? mkkey(dv[0], iv[0]) : ~0ull;
    u64 k1 = (2 * l31 + 1 < c) ? mkkey(dv[1], iv[1]) : ~0ull;
    bitonic64k(k0, k1, l31);
    u64 a = __shfl(k0, l31 >> 1, 32);
    u64 b2 = __shfl(k1, l31 >> 1, 32);
    u64 kv = (l31 & 1) ? b2 : a;              // element l31 of sorted order
    if (l31 < KK) {
      size_t rowg = ((size_t)b * NN + n0w + rloc) * SS + slice;
      keys2[rowg * KK + l31] = kv;
    }
  }
}

// ---------------- merge two sorted 20-key lists per row ----------------
__global__ void __launch_bounds__(256) merge_kernel(
    const u64* __restrict__ keys2, int* __restrict__ idxOut)
{
  int row = blockIdx.x * 256 + threadIdx.x;   // 0..32767
  if (row >= BB * NN) return;
  u64 h[SS]; int p[SS];
  #pragma unroll
  for (int s = 0; s < SS; ++s) {
    p[s] = 0;
    h[s] = keys2[((size_t)row * SS + s) * KK];
  }
  int* op = idxOut + (size_t)row * KK;
  #pragma unroll
  for (int q = 0; q < KK; ++q) {
    int bs = 0;
    u64 bv = h[0];
    #pragma unroll
    for (int s = 1; s < SS; ++s) { if (h[s] < bv) { bv = h[s]; bs = s; } }
    op[q] = (int)(bv & 0xFFFFull);            // col in low 16 bits
    p[bs]++;
    h[bs] = (p[bs] < KK) ? keys2[((size_t)row * SS + bs) * KK + p[bs]] : ~0ull;
  }
}

// ---------------- gather: out[b,o,n] = P + max_j Q[nbr_j] ----------------
__global__ void __launch_bounds__(256) gather_kernel(
    const float* __restrict__ x, const float* __restrict__ W,
    const float* __restrict__ bias,
    const float* __restrict__ Q, const int* __restrict__ idxIn,
    float* __restrict__ out)
{
  __shared__ float xs[64][65];
  __shared__ float wp[64][65];
  __shared__ float ot[64][65];
  __shared__ float bs[64];
  int t = threadIdx.x;
  int b = blockIdx.x >> 6;
  int n0 = (blockIdx.x & 63) << 6;
  const float* xb = x + (size_t)b * FF * NN;

  int nl0 = t & 63, fq = t >> 6;
  #pragma unroll
  for (int i = 0; i < 16; ++i) {
    int f = fq + i * 4;
    xs[f][nl0] = xb[(size_t)f * NN + n0 + nl0];
  }
  #pragma unroll
  for (int i = 0; i < 16; ++i) {
    int id = i * 256 + t;            // 0..4095
    int o = id >> 6, f = id & 63;
    wp[o][f] = W[o * 128 + f] - W[o * 128 + 64 + f];   // W1 - W2
  }
  if (t < 64) bs[t] = bias[t];
  __syncthreads();

  int o = t & 63, g = t >> 6;
  for (int i = 0; i < 16; ++i) {
    int nl = g + i * 4;
    int n = n0 + nl;
    float p = bs[o];
    #pragma unroll
    for (int f = 0; f < FF; ++f) p += wp[o][f] * xs[f][nl];
    const int* ip = idxIn + ((size_t)b * NN + n) * KK;
    float m = -FLT_MAX;
    #pragma unroll
    for (int j = 0; j < KK; ++j) {
      int nb = ip[j];                                   // wave-uniform
      m = fmaxf(m, Q[((size_t)b * NN + nb) * FF + o]);  // 256B coalesced
    }
    ot[nl][o] = p + m;
  }
  __syncthreads();
  for (int i = 0; i < 16; ++i) {
    int o2 = g + i * 4;
    int nl = t & 63;
    out[((size_t)b * FF + o2) * NN + n0 + nl] = ot[nl][o2];
  }
}

extern "C" void kernel_launch(void* const* d_in, const int* in_sizes, int n_in,
                              void* d_out, int out_size, void* d_ws, size_t ws_size,
                              hipStream_t stream)
{
  const float* x    = (const float*)d_in[0];
  const float* W    = (const float*)d_in[1];
  const float* bias = (const float*)d_in[2];
  float* out = (float*)d_out;

  int*   idxb = (int*)d_ws;                               // 8*4096*20
  float* sq   = (float*)(idxb + (size_t)BB * NN * KK);    // 8*4096
  float* Q    = sq + (size_t)BB * NN;                     // 8*4096*64
  ushort_t* ph = (ushort_t*)(Q + (size_t)BB * NN * FF);   // 8*4096*64 each
  ushort_t* pm = ph + (size_t)BB * NN * FF;
  u64*   keys2 = (u64*)(pm + (size_t)BB * NN * FF);       // 8*4096*2*20

  prep_kernel<<<BB * (NN / 64), 256, 0, stream>>>(x, W, sq, Q, ph, pm);
  knn_kernel<<<BB * 64 * SS, 256, 0, stream>>>(ph, pm, sq, keys2);   // 1024 blocks
  merge_kernel<<<(BB * NN + 255) / 256, 256, 0, stream>>>(keys2, idxb);
  gather_kernel<<<BB * (NN / 64), 256, 0, stream>>>(x, W, bias, Q, idxb, out);
}

// Round 8
// 256.408 us; speedup vs baseline: 1.1395x; 1.0286x over previous
//
#include <hip/hip_runtime.h>
#include <hip/hip_bf16.h>
#include <float.h>

// EdgeConv (fp32 I/O):
//   out[b,o,n] = P[b,n,o] + max_{j<20} Q[b, idx[b,n,j], o]
//   P = (W1-W2)^T x + b ; Q = W2^T x
//   knn: top-20 smallest of score[m] = sq[m] - 2*x_n.x_m  (m != n)
// Round 22 (cache-BW theory): R7 audit: 3.1 GB of B-panel reads/dispatch
// at 18.9 TB/s == L3 ceiling; all 4 waves/block stream IDENTICAL data.
// Changes:
//  - double-buffered LDS staging of B panels (4 KB passA / 8 KB passB per
//    chunk), issue-early/write-late, one barrier per chunk. VMEM 3.1 GB ->
//    0.79 GB; fragment reads now LDS (conflict-free 64x16B).
//  - CAP 64 -> 60: LDS total 39.7 KB -> keeps 4 blocks/CU (16 waves/CU).
//  - XCD-affine swizzle: b = blk&7 -> per-XCD working set 1 MB (L2-fit).
// tau = 20th of 32-pool (+PAD 0.3 >= fp16-hi err 0.125). Ballot compact.
// Planes hold y = sqrt(2)*x fp16x2, tiled [b][n>>4][k>>3][n&15][k&7].

#define BB 8
#define FF 64
#define NN 4096
#define KK 20
#define CAP 60
#define SS 2
#define PAD 0.3f

typedef unsigned short ushort_t;
typedef unsigned long long u64;
typedef __attribute__((ext_vector_type(8))) _Float16 half8;
typedef __attribute__((ext_vector_type(4))) float floatx4;
typedef __attribute__((ext_vector_type(2))) float floatx2;
typedef __attribute__((ext_vector_type(2))) unsigned short ushortx2;
typedef __attribute__((ext_vector_type(4))) unsigned int uintx4;

// plane flat index (shorts): [b][n>>4][k>>3][n&15][k&7]
__device__ __forceinline__ size_t plidx16(int b, int n, int k) {
  return ((size_t)b * 256 + (n >> 4)) * 1024 + (size_t)(k >> 3) * 128 + (size_t)(n & 15) * 8 + (k & 7);
}

// ---------------- prep: sq, Q, fp16x2 planes of y = sqrt(2)*x ----------------
__global__ void __launch_bounds__(256) prep_kernel(
    const float* __restrict__ x, const float* __restrict__ W,
    float* __restrict__ sq, float* __restrict__ Q,
    ushort_t* __restrict__ ph, ushort_t* __restrict__ pm)
{
  __shared__ float xs[64][65];
  __shared__ float w2[64][65];
  int t = threadIdx.x;
  int b = blockIdx.x >> 6;
  int n0 = (blockIdx.x & 63) << 6;
  const float* xb = x + (size_t)b * FF * NN;

  int nl = t & 63, fq = t >> 6;
  #pragma unroll
  for (int i = 0; i < 16; ++i) {
    int f = fq + i * 4;
    xs[f][nl] = xb[(size_t)f * NN + n0 + nl];
  }
  #pragma unroll
  for (int i = 0; i < 16; ++i) {
    int id = i * 256 + t;            // 0..4095
    int o = id >> 6, f = id & 63;
    w2[o][f] = W[o * 128 + 64 + f];  // W2
  }
  __syncthreads();

  if (t < 64) {
    float s = 0.f;
    #pragma unroll
    for (int f = 0; f < FF; ++f) { float v = xs[f][t]; s += v * v; }
    sq[b * NN + n0 + t] = s;
  }
  int o = t & 63, g = t >> 6;
  for (int i = 0; i < 16; ++i) {
    int r = g + i * 4;
    int n = n0 + r;
    float acc = 0.f;
    #pragma unroll
    for (int f = 0; f < FF; ++f) acc += w2[o][f] * xs[f][r];
    Q[((size_t)b * NN + n) * FF + o] = acc;

    // fp16x2 split of y = sqrt(2)*x: y = h + m*2^-12 (m stored pre-scaled by 4096)
    float v = xs[o][r] * 1.41421356237309515f;
    _Float16 hh = (_Float16)v;
    float hf = (float)hh;
    _Float16 mm = (_Float16)((v - hf) * 4096.0f);
    size_t pb = plidx16(b, n, o);
    ph[pb] = __builtin_bit_cast(unsigned short, hh);
    pm[pb] = __builtin_bit_cast(unsigned short, mm);
  }
}

// ascending bitonic sort of 32 floats as elements (2l, 2l+1) across 16 lanes
__device__ __forceinline__ void bitonic32f(float& v0, float& v1, int l15)
{
  #pragma unroll
  for (int k = 2; k <= 32; k <<= 1) {
    #pragma unroll
    for (int j = k >> 1; j >= 1; j >>= 1) {
      bool dirup = ((2 * l15) & k) == 0;
      if (j >= 2) {
        int lj = j >> 1;
        float p0 = __shfl_xor(v0, lj, 16);
        float p1 = __shfl_xor(v1, lj, 16);
        bool lower = (l15 & lj) == 0;
        bool keepmin = (dirup == lower);
        v0 = keepmin ? fminf(v0, p0) : fmaxf(v0, p0);
        v1 = keepmin ? fminf(v1, p1) : fmaxf(v1, p1);
      } else {
        float lo = fminf(v0, v1), hi = fmaxf(v0, v1);
        v0 = dirup ? lo : hi;
        v1 = dirup ? hi : lo;
      }
    }
  }
}

// ascending bitonic sort of 64 u64 keys as elements (2l, 2l+1) across 32 lanes
__device__ __forceinline__ void bitonic64k(u64& v0, u64& v1, int l31)
{
  #pragma unroll
  for (int k = 2; k <= 64; k <<= 1) {
    #pragma unroll
    for (int j = k >> 1; j >= 1; j >>= 1) {
      bool dirup = ((2 * l31) & k) == 0;
      if (j >= 2) {
        int lj = j >> 1;
        u64 p0 = __shfl_xor(v0, lj, 32);
        u64 p1 = __shfl_xor(v1, lj, 32);
        bool lower = (l31 & lj) == 0;
        bool keepmin = (dirup == lower);
        u64 a0 = v0 < p0 ? v0 : p0, b0 = v0 < p0 ? p0 : v0;
        u64 a1 = v1 < p1 ? v1 : p1, b1 = v1 < p1 ? p1 : v1;
        v0 = keepmin ? a0 : b0;
        v1 = keepmin ? a1 : b1;
      } else {
        u64 lo = v0 < v1 ? v0 : v1, hi = v0 < v1 ? v1 : v0;
        v0 = dirup ? lo : hi;
        v1 = dirup ? hi : lo;
      }
    }
  }
}

// monotone u64 key: (order-preserving f32 bits << 16) | col (col < 4096)
__device__ __forceinline__ u64 mkkey(float d, unsigned short idx)
{
  unsigned ub = __float_as_uint(d);
  unsigned mono = ub ^ (0x80000000u | (unsigned)((int)ub >> 31));
  return ((u64)mono << 16) | idx;
}

// ---------------- knn: two-pass threshold filter, 16 rows/wave ----------------
__global__ void __launch_bounds__(256) knn_kernel(
    const ushort_t* __restrict__ ph, const ushort_t* __restrict__ pm,
    const float* __restrict__ sq, u64* __restrict__ keys2)
{
  __shared__ ushort_t stg[2][2][2048];    // 16384 B  [dbuf][plane][shorts]
  __shared__ float    bufd[4][16][CAP];   // 15360 B
  __shared__ ushort_t bufi[4][16][CAP];   //  7680 B
  __shared__ int scnt[4][16];             //   256 B   (total 39680 B)

  const int t = threadIdx.x;
  const int lane = t & 63;
  const int l15 = lane & 15;
  const int q = lane >> 4;          // quarter 0..3 (C rows 4q..4q+3)
  const int wv = t >> 6;
  const int blk = blockIdx.x;
  // XCD-affine: consecutive blockIdx round-robin across 8 XCDs -> give each
  // XCD one batch b; per-XCD panel working set = 1 MB (L2-resident).
  const int b = blk & 7;
  const int k2 = blk >> 3;
  const int slice = k2 & 1;         // SS=2 half-slices of 2048 candidates
  const int g = k2 >> 1;            // 64 groups per batch
  const int n0w = (g * 4 + wv) * 16;   // this wave's 16-row tile

  const float* __restrict__ sqb = sq + (size_t)b * NN;
  const float MS = 2.44140625e-4f;   // 2^-12
  const int laneoff = q * 128 + l15 * 8;

  // diagonal (self) lives in exactly one chunk of one slice for this wave
  const bool hasdiag = ((n0w >> 11) == slice);
  const int dmc = (n0w & 2047) >> 5;

  // resident A fragments: row = l15, k = 32s + 8q + e ; NEGATED so the MFMA
  // accumulates  sq_m - y_n.y_m  directly (C-init = sq_m).
  half8 Ah[2], Am[2];
  {
    size_t abase = ((size_t)b * 256 + (n0w >> 4)) * 1024 + laneoff;
    #pragma unroll
    for (int s = 0; s < 2; ++s) {
      Ah[s] = *(const half8*)(ph + abase + s * 512);
      Am[s] = *(const half8*)(pm + abase + s * 512);
      uintx4 uh = __builtin_bit_cast(uintx4, Ah[s]); uh ^= 0x80008000u;
      uintx4 um = __builtin_bit_cast(uintx4, Am[s]); um ^= 0x80008000u;
      Ah[s] = __builtin_bit_cast(half8, uh);
      Am[s] = __builtin_bit_cast(half8, um);
    }
  }

  // B-panel base for this (b, slice): contiguous 131072 shorts; chunk = 2048
  const size_t slb = (size_t)b * 262144 + (size_t)slice * 131072;
  const uintx4* gph = (const uintx4*)(ph + slb) + t;   // chunk stride = 256 uintx4
  const uintx4* gpm = (const uintx4*)(pm + slb) + t;

  // -------- pass A (fp16-hi only): per-lane min2 per row over 64 chunks --------
  // pool = 32 values (16 lanes x best-2 of ti-merged per-chunk minima);
  // 20 smallest pool entries are distinct candidates -> >=20 cands <= tau.
  float m1[4], m2[4];
  #pragma unroll
  for (int r = 0; r < 4; ++r) { m1[r] = FLT_MAX; m2[r] = FLT_MAX; }

  {
    // prologue: stage chunk 0 (ph only)
    uintx4 v0s = gph[0];
    *((uintx4*)stg[0][0] + t) = v0s;
    __syncthreads();

    const float* psq = sqb + slice * 2048 + l15;
    for (int mc = 0; mc < 64; ++mc) {
      const int cur = mc & 1;
      uintx4 nx;
      if (mc < 63) nx = gph[(mc + 1) * 256];        // issue early
      float sv0 = psq[0];
      float sv1 = psq[16];
      floatx4 a1[2];
      #pragma unroll
      for (int e = 0; e < 4; ++e) { a1[0][e] = sv0; a1[1][e] = sv1; }
      const ushort_t* sp = stg[cur][0] + laneoff;
      #pragma unroll
      for (int ti = 0; ti < 2; ++ti) {
        #pragma unroll
        for (int s = 0; s < 2; ++s) {
          half8 Bh = *(const half8*)(sp + ti * 1024 + s * 512);
          a1[ti] = __builtin_amdgcn_mfma_f32_16x16x32_f16(Ah[s], Bh, a1[ti], 0, 0, 0);
        }
      }
      if (hasdiag && mc == dmc) {
        const int m0 = slice * 2048 + mc * 32;
        #pragma unroll
        for (int ti = 0; ti < 2; ++ti) {
          int mcol = m0 + 16 * ti + l15;
          #pragma unroll
          for (int r = 0; r < 4; ++r)
            if (mcol == n0w + 4 * q + r) a1[ti][r] = FLT_MAX;
        }
      }
      #pragma unroll
      for (int r = 0; r < 4; ++r) {
        float c = fminf(a1[0][r], a1[1][r]);
        m2[r] = __builtin_amdgcn_fmed3f(c, m1[r], m2[r]);  // min2 update
        m1[r] = fminf(m1[r], c);
      }
      if (mc < 63) *((uintx4*)stg[cur ^ 1][0] + t) = nx;   // write late
      __syncthreads();
      psq += 32;
    }
  }

  // tau_r = 20th of 32-pool (approx) + PAD; PAD >= fp16-hi distance error
  float taupad[4];
  #pragma unroll
  for (int r = 0; r < 4; ++r) {
    float v0 = m1[r], v1 = m2[r];
    bitonic32f(v0, v1, l15);
    taupad[r] = __shfl(v1, 9, 16) + PAD;   // element 19 = lane 9, reg 1
  }

  // -------- pass B: exact fp16x2 recompute, ballot-compact into LDS --------
  int cnt[4];
  #pragma unroll
  for (int r = 0; r < 4; ++r) cnt[r] = 0;

  {
    // prologue: stage chunk 0 (both planes)
    uintx4 vh0 = gph[0];
    uintx4 vm0 = gpm[0];
    *((uintx4*)stg[0][0] + t) = vh0;
    *((uintx4*)stg[0][1] + t) = vm0;
    __syncthreads();

    const float* psq = sqb + slice * 2048 + l15;
    for (int mc = 0; mc < 64; ++mc) {
      const int cur = mc & 1;
      uintx4 nh, nm;
      if (mc < 63) { nh = gph[(mc + 1) * 256]; nm = gpm[(mc + 1) * 256]; }
      float sv0 = psq[0];
      float sv1 = psq[16];
      floatx4 a1[2], a2[2];
      #pragma unroll
      for (int e = 0; e < 4; ++e) {
        a1[0][e] = sv0; a1[1][e] = sv1;
        a2[0][e] = 0.f; a2[1][e] = 0.f;
      }
      const ushort_t* sp0 = stg[cur][0] + laneoff;
      const ushort_t* sp1 = stg[cur][1] + laneoff;
      #pragma unroll
      for (int ti = 0; ti < 2; ++ti) {
        #pragma unroll
        for (int s = 0; s < 2; ++s) {
          half8 Bh = *(const half8*)(sp0 + ti * 1024 + s * 512);
          half8 Bm = *(const half8*)(sp1 + ti * 1024 + s * 512);
          a1[ti] = __builtin_amdgcn_mfma_f32_16x16x32_f16(Ah[s], Bh, a1[ti], 0, 0, 0);
          a2[ti] = __builtin_amdgcn_mfma_f32_16x16x32_f16(Am[s], Bh, a2[ti], 0, 0, 0);
          a2[ti] = __builtin_amdgcn_mfma_f32_16x16x32_f16(Ah[s], Bm, a2[ti], 0, 0, 0);
        }
      }
      // exact cand = a1 + MS*a2, in place
      #pragma unroll
      for (int ti = 0; ti < 2; ++ti)
        #pragma unroll
        for (int r = 0; r < 4; ++r)
          a1[ti][r] = __builtin_fmaf(MS, a2[ti][r], a1[ti][r]);
      const int m0 = slice * 2048 + mc * 32;
      if (hasdiag && mc == dmc) {
        #pragma unroll
        for (int ti = 0; ti < 2; ++ti) {
          int mcol = m0 + 16 * ti + l15;
          #pragma unroll
          for (int r = 0; r < 4; ++r)
            if (mcol == n0w + 4 * q + r) a1[ti][r] = FLT_MAX;
        }
      }
      #pragma unroll
      for (int ti = 0; ti < 2; ++ti) {
        int mcol = m0 + 16 * ti + l15;
        #pragma unroll
        for (int r = 0; r < 4; ++r) {
          bool ok = a1[ti][r] <= taupad[r];
          unsigned long long bal = __ballot(ok);
          if (bal) {                       // wave-uniform skip of empty groups
            unsigned mh = (unsigned)((bal >> (q * 16)) & 0xFFFFull);
            int pre = __popc(mh & ((1u << l15) - 1u));
            int slot = cnt[r] + pre;
            if (ok && slot < CAP) {
              bufd[wv][4 * q + r][slot] = a1[ti][r];
              bufi[wv][4 * q + r][slot] = (ushort_t)mcol;
            }
            cnt[r] += __popc(mh);
          }
        }
      }
      if (mc < 63) {
        *((uintx4*)stg[cur ^ 1][0] + t) = nh;
        *((uintx4*)stg[cur ^ 1][1] + t) = nm;
      }
      __syncthreads();
      psq += 32;
    }
  }

  if (l15 == 0) {
    #pragma unroll
    for (int r = 0; r < 4; ++r) scnt[wv][4 * q + r] = cnt[r];
  }
  __builtin_amdgcn_s_waitcnt(0);   // drain LDS writes (same-wave read below)

  // -------- final: per half-wave, sort 8 rows' survivors, emit sorted top-20 --------
  const int l31 = t & 31;
  const int hfw = (t >> 5) & 1;
  #pragma unroll
  for (int i = 0; i < 8; ++i) {
    int rloc = hfw * 8 + i;
    int c = scnt[wv][rloc];
    c = c < CAP ? c : CAP;
    u64 k0 = ~0ull, k1 = ~0ull;
    if (2 * l31 < c) {
      floatx2  dv = *(const floatx2*)&bufd[wv][rloc][2 * l31];
      ushortx2 iv = *(const ushortx2*)&bufi[wv][rloc][2 * l31];
      k0 = mkkey(dv[0], iv[0]);
      if (2 * l31 + 1 < c) k1 = mkkey(dv[1], iv[1]);
    }
    bitonic64k(k0, k1, l31);
    u64 a = __shfl(k0, l31 >> 1, 32);
    u64 b2 = __shfl(k1, l31 >> 1, 32);
    u64 kv = (l31 & 1) ? b2 : a;              // element l31 of sorted order
    if (l31 < KK) {
      size_t rowg = ((size_t)b * NN + n0w + rloc) * SS + slice;
      keys2[rowg * KK + l31] = kv;
    }
  }
}

// ---------------- merge two sorted 20-key lists per row ----------------
__global__ void __launch_bounds__(256) merge_kernel(
    const u64* __restrict__ keys2, int* __restrict__ idxOut)
{
  int row = blockIdx.x * 256 + threadIdx.x;   // 0..32767
  if (row >= BB * NN) return;
  u64 h[SS]; int p[SS];
  #pragma unroll
  for (int s = 0; s < SS; ++s) {
    p[s] = 0;
    h[s] = keys2[((size_t)row * SS + s) * KK];
  }
  int* op = idxOut + (size_t)row * KK;
  #pragma unroll
  for (int q = 0; q < KK; ++q) {
    int bs = 0;
    u64 bv = h[0];
    #pragma unroll
    for (int s = 1; s < SS; ++s) { if (h[s] < bv) { bv = h[s]; bs = s; } }
    op[q] = (int)(bv & 0xFFFFull);            // col in low 16 bits
    p[bs]++;
    h[bs] = (p[bs] < KK) ? keys2[((size_t)row * SS + bs) * KK + p[bs]] : ~0ull;
  }
}

// ---------------- gather: out[b,o,n] = P + max_j Q[nbr_j] ----------------
__global__ void __launch_bounds__(256) gather_kernel(
    const float* __restrict__ x, const float* __restrict__ W,
    const float* __restrict__ bias,
    const float* __restrict__ Q, const int* __restrict__ idxIn,
    float* __restrict__ out)
{
  __shared__ float xs[64][65];
  __shared__ float wp[64][65];
  __shared__ float ot[64][65];
  __shared__ float bs[64];
  int t = threadIdx.x;
  int b = blockIdx.x >> 6;
  int n0 = (blockIdx.x & 63) << 6;
  const float* xb = x + (size_t)b * FF * NN;

  int nl0 = t & 63, fq = t >> 6;
  #pragma unroll
  for (int i = 0; i < 16; ++i) {
    int f = fq + i * 4;
    xs[f][nl0] = xb[(size_t)f * NN + n0 + nl0];
  }
  #pragma unroll
  for (int i = 0; i < 16; ++i) {
    int id = i * 256 + t;            // 0..4095
    int o = id >> 6, f = id & 63;
    wp[o][f] = W[o * 128 + f] - W[o * 128 + 64 + f];   // W1 - W2
  }
  if (t < 64) bs[t] = bias[t];
  __syncthreads();

  int o = t & 63, g = t >> 6;
  for (int i = 0; i < 16; ++i) {
    int nl = g + i * 4;
    int n = n0 + nl;
    float p = bs[o];
    #pragma unroll
    for (int f = 0; f < FF; ++f) p += wp[o][f] * xs[f][nl];
    const int* ip = idxIn + ((size_t)b * NN + n) * KK;
    float m = -FLT_MAX;
    #pragma unroll
    for (int j = 0; j < KK; ++j) {
      int nb = ip[j];                                   // wave-uniform
      m = fmaxf(m, Q[((size_t)b * NN + nb) * FF + o]);  // 256B coalesced
    }
    ot[nl][o] = p + m;
  }
  __syncthreads();
  for (int i = 0; i < 16; ++i) {
    int o2 = g + i * 4;
    int nl = t & 63;
    out[((size_t)b * FF + o2) * NN + n0 + nl] = ot[nl][o2];
  }
}

extern "C" void kernel_launch(void* const* d_in, const int* in_sizes, int n_in,
                              void* d_out, int out_size, void* d_ws, size_t ws_size,
                              hipStream_t stream)
{
  const float* x    = (const float*)d_in[0];
  const float* W    = (const float*)d_in[1];
  const float* bias = (const float*)d_in[2];
  float* out = (float*)d_out;

  int*   idxb = (int*)d_ws;                               // 8*4096*20
  float* sq   = (float*)(idxb + (size_t)BB * NN * KK);    // 8*4096
  float* Q    = sq + (size_t)BB * NN;                     // 8*4096*64
  ushort_t* ph = (ushort_t*)(Q + (size_t)BB * NN * FF);   // 8*4096*64 each
  ushort_t* pm = ph + (size_t)BB * NN * FF;
  u64*   keys2 = (u64*)(pm + (size_t)BB * NN * FF);       // 8*4096*2*20

  prep_kernel<<<BB * (NN / 64), 256, 0, stream>>>(x, W, sq, Q, ph, pm);
  knn_kernel<<<BB * 64 * SS, 256, 0, stream>>>(ph, pm, sq, keys2);   // 1024 blocks
  merge_kernel<<<(BB * NN + 255) / 256, 256, 0, stream>>>(keys2, idxb);
  gather_kernel<<<BB * (NN / 64), 256, 0, stream>>>(x, W, bias, Q, idxb, out);
}